// Round 1
// baseline (3516.582 us; speedup 1.0000x reference)
//
#include <hip/hip_runtime.h>

#define NN 100000
#define NE 1000000
#define FC 64
#define NCLS 32
#define MMAX_INIT 0x007FFFFFu  // f2o(-inf)
#define EPAD 68

__device__ __forceinline__ unsigned f2o(float f){
  unsigned b = __float_as_uint(f);
  return (b & 0x80000000u) ? ~b : (b | 0x80000000u);
}
__device__ __forceinline__ float o2f(unsigned u){
  return (u & 0x80000000u) ? __uint_as_float(u & 0x7fffffffu) : __uint_as_float(~u);
}

// ---- init aggregation buffers ----
__global__ void k_init(float* __restrict__ msum, unsigned* __restrict__ mmax,
                       float* __restrict__ cnt, int do_cnt){
  int i = blockIdx.x*256 + threadIdx.x;
  if (i < NN*FC){ msum[i] = 0.f; mmax[i] = MMAX_INIT; }
  if (do_cnt && i < NN) cnt[i] = 0.f;
}

// ---- in-degree (shared by both layers) ----
__global__ void k_count(const int* __restrict__ dst, float* __restrict__ cnt){
  int e = blockIdx.x*256 + threadIdx.x;
  if (e < NE) atomicAdd(&cnt[dst[e]], 1.0f);
}

// ---- fold post+lin:  WcT[k][o] = sum_j Wlin[o][j]*Wpost[j][k]; bc = Wlin*bpost + blin ----
__global__ void k_prep(const float* __restrict__ Wlin, const float* __restrict__ blin,
                       const float* __restrict__ Wpost, const float* __restrict__ bpost,
                       float* __restrict__ WcT, float* __restrict__ bc){
  int t = blockIdx.x*256 + threadIdx.x;
  if (t < 256*FC){
    int k = t >> 6, o = t & 63;
    float s = 0.f;
    #pragma unroll 8
    for (int j = 0; j < 64; j++) s += Wlin[o*64+j] * Wpost[j*256+k];
    WcT[t] = s;                      // t == k*64+o
  }
  if (t < FC){
    float s = blin[t];
    for (int j = 0; j < 64; j++) s += Wlin[t*64+j] * bpost[j];
    bc[t] = s;
  }
}

// ---- fused edge message GEMM + atomic aggregation ----
// tile: 64 edges x 64 outputs, K=128 (concat(x[dst],x[src]))
__global__ __launch_bounds__(256, 2) void k_edge(
    const float* __restrict__ xin, const int* __restrict__ src,
    const int* __restrict__ dst,
    const float* __restrict__ Wpre, const float* __restrict__ bpre,
    float* __restrict__ msum, unsigned* __restrict__ mmax){
  __shared__ float As[128][EPAD];   // As[k][e] gathered features (transposed)
  __shared__ float Bs[128][EPAD];   // Bs[k][o] = Wpre[o][k]
  __shared__ int   dstS[64];
  __shared__ float bS[64];
  const int tid = threadIdx.x;

  // stage Wpre^T once per block (coalesced global read)
  for (int i = tid; i < 64*128; i += 256){
    int o = i >> 7, k = i & 127;
    Bs[k][o] = Wpre[i];
  }
  if (tid < 64) bS[tid] = bpre[tid];

  const int to = tid & 15, te = tid >> 4;
  const int numTiles = NE / 64;
  for (int tile = blockIdx.x; tile < numTiles; tile += gridDim.x){
    const int ebase = tile * 64;
    __syncthreads();   // protect As/dstS from previous iteration
    // stage gathered feature tile: rows are coalesced 256B reads
    for (int i = tid; i < 64*128; i += 256){
      int e = i >> 7, k = i & 127;
      int node = (k < 64) ? dst[ebase+e] : src[ebase+e];
      As[k][e] = xin[node*64 + (k & 63)];
    }
    if (tid < 64) dstS[tid] = dst[ebase + tid];
    __syncthreads();

    float acc[4][4];
    #pragma unroll
    for (int i = 0; i < 4; i++)
      #pragma unroll
      for (int j = 0; j < 4; j++) acc[i][j] = 0.f;

    #pragma unroll 4
    for (int k = 0; k < 128; k++){
      float4 a = *(const float4*)&As[k][te*4];
      float4 b = *(const float4*)&Bs[k][to*4];
      acc[0][0] += a.x*b.x; acc[0][1] += a.x*b.y; acc[0][2] += a.x*b.z; acc[0][3] += a.x*b.w;
      acc[1][0] += a.y*b.x; acc[1][1] += a.y*b.y; acc[1][2] += a.y*b.z; acc[1][3] += a.y*b.w;
      acc[2][0] += a.z*b.x; acc[2][1] += a.z*b.y; acc[2][2] += a.z*b.z; acc[2][3] += a.z*b.w;
      acc[3][0] += a.w*b.x; acc[3][1] += a.w*b.y; acc[3][2] += a.w*b.z; acc[3][3] += a.w*b.w;
    }

    // epilogue: atomic sum + max aggregation at dst nodes
    #pragma unroll
    for (int i = 0; i < 4; i++){
      int d = dstS[te*4 + i];
      #pragma unroll
      for (int j = 0; j < 4; j++){
        float m = acc[i][j] + bS[to*4 + j];
        int addr = d*FC + to*4 + j;
        atomicAdd(&msum[addr], m);
        atomicMax(&mmax[addr], f2o(m));
      }
    }
  }
}

// ---- per-node: z=[x|mean|max|sum] (256) -> Wc(64x256)z + bc, optional relu ----
__global__ __launch_bounds__(256, 2) void k_post(
    const float* __restrict__ xin, const float* __restrict__ msum,
    const unsigned* __restrict__ mmax, const float* __restrict__ cnt,
    const float* __restrict__ WcT, const float* __restrict__ bc,
    float* __restrict__ out, int relu){
  __shared__ float W[256*64];       // W[k][o]
  __shared__ float zb[4][256];
  __shared__ float bS[64];
  const int tid = threadIdx.x;
  for (int i = tid; i < 256*64; i += 256) W[i] = WcT[i];
  if (tid < 64) bS[tid] = bc[tid];
  __syncthreads();

  const int w = tid >> 6, lane = tid & 63;
  const int stride = gridDim.x * 4;
  const int nit = (NN + stride - 1) / stride;
  int node = blockIdx.x*4 + w;
  for (int it = 0; it < nit; it++, node += stride){
    bool act = node < NN;
    if (act){
      float xv = xin[node*FC + lane];
      float sv = msum[node*FC + lane];
      float c  = cnt[node];
      float mean = sv / fmaxf(c, 1.f);
      float mx = o2f(mmax[node*FC + lane]);
      if (!(c > 0.f)) mx = 0.f;       // empty segment -> 0 (PyG)
      zb[w][lane]       = xv;
      zb[w][64 + lane]  = mean;
      zb[w][128 + lane] = mx;
      zb[w][192 + lane] = sv;
    }
    __syncthreads();
    if (act){
      float acc = bS[lane];
      #pragma unroll 8
      for (int kb = 0; kb < 64; kb++){
        float4 z = *(const float4*)&zb[w][kb*4];
        const float* wp = &W[kb*4*64 + lane];
        acc += wp[0]*z.x + wp[64]*z.y + wp[128]*z.z + wp[192]*z.w;
      }
      out[node*FC + lane] = relu ? fmaxf(acc, 0.f) : acc;
    }
    __syncthreads();
  }
}

// ---- classifier: out[n][c] = bf[c] + sum_k Wf[c][k] h[n][k] ----
__global__ __launch_bounds__(256, 2) void k_cls(
    const float* __restrict__ h, const float* __restrict__ Wf,
    const float* __restrict__ bfv, float* __restrict__ out){
  __shared__ float WT[64*NCLS];     // WT[k][c]
  __shared__ float hS[4][2][64];
  __shared__ float bS[NCLS];
  const int tid = threadIdx.x;
  for (int i = tid; i < 64*NCLS; i += 256){
    int k = i >> 5, c = i & 31;
    WT[k*NCLS + c] = Wf[c*64 + k];
  }
  if (tid < NCLS) bS[tid] = bfv[tid];
  __syncthreads();

  const int w = tid >> 6, lane = tid & 63;
  const int half = lane >> 5, c = lane & 31;
  const int npairs = NN / 2;
  const int stride = gridDim.x * 4;
  const int nit = (npairs + stride - 1) / stride;
  int pair = blockIdx.x*4 + w;
  for (int it = 0; it < nit; it++, pair += stride){
    bool act = pair < npairs;
    if (act){
      hS[w][0][lane] = h[(2*pair)  *64 + lane];
      hS[w][1][lane] = h[(2*pair+1)*64 + lane];
    }
    __syncthreads();
    if (act){
      float acc = bS[c];
      #pragma unroll 8
      for (int k = 0; k < 64; k++)
        acc += WT[k*NCLS + c] * hS[w][half][k];
      out[(2*pair + half)*NCLS + c] = acc;
    }
    __syncthreads();
  }
}

extern "C" void kernel_launch(void* const* d_in, const int* in_sizes, int n_in,
                              void* d_out, int out_size, void* d_ws, size_t ws_size,
                              hipStream_t stream){
  const float* x      = (const float*)d_in[0];
  const int*   ei     = (const int*)  d_in[1];
  const int*   src    = ei;
  const int*   dst    = ei + NE;
  const float* W1_pre = (const float*)d_in[2];
  const float* b1_pre = (const float*)d_in[3];
  const float* W1_post= (const float*)d_in[4];
  const float* b1_post= (const float*)d_in[5];
  const float* W1_lin = (const float*)d_in[6];
  const float* b1_lin = (const float*)d_in[7];
  const float* W2_pre = (const float*)d_in[8];
  const float* b2_pre = (const float*)d_in[9];
  const float* W2_post= (const float*)d_in[10];
  const float* b2_post= (const float*)d_in[11];
  const float* W2_lin = (const float*)d_in[12];
  const float* b2_lin = (const float*)d_in[13];
  const float* Wf     = (const float*)d_in[14];
  const float* bf     = (const float*)d_in[15];
  float* out = (float*)d_out;

  size_t off = 0;
  char* ws = (char*)d_ws;
  auto alloc = [&](size_t elems){ void* p = ws + off; off += elems*4; return p; };
  float*    msum = (float*)   alloc((size_t)NN*FC);
  unsigned* mmax = (unsigned*)alloc((size_t)NN*FC);
  float*    cnt  = (float*)   alloc(NN);
  float*    h1   = (float*)   alloc((size_t)NN*FC);
  float*    Wc1T = (float*)   alloc(256*64);
  float*    bc1  = (float*)   alloc(64);
  float*    Wc2T = (float*)   alloc(256*64);
  float*    bc2  = (float*)   alloc(64);
  float* h2;
  if (off + (size_t)NN*FC*4 <= ws_size) h2 = (float*)alloc((size_t)NN*FC);
  else h2 = msum;  // safe alias: each lane of k_post reads msum only at the address it writes

  const int INIT_GRID = (NN*FC + 255)/256;

  k_prep<<<64, 256, 0, stream>>>(W1_lin, b1_lin, W1_post, b1_post, Wc1T, bc1);
  k_prep<<<64, 256, 0, stream>>>(W2_lin, b2_lin, W2_post, b2_post, Wc2T, bc2);
  k_init<<<INIT_GRID, 256, 0, stream>>>(msum, mmax, cnt, 1);
  k_count<<<(NE + 255)/256, 256, 0, stream>>>(dst, cnt);

  // layer 1
  k_edge<<<2048, 256, 0, stream>>>(x, src, dst, W1_pre, b1_pre, msum, mmax);
  k_post<<<2048, 256, 0, stream>>>(x, msum, mmax, cnt, Wc1T, bc1, h1, 1);

  // layer 2
  k_init<<<INIT_GRID, 256, 0, stream>>>(msum, mmax, cnt, 0);
  k_edge<<<2048, 256, 0, stream>>>(h1, src, dst, W2_pre, b2_pre, msum, mmax);
  k_post<<<2048, 256, 0, stream>>>(h1, msum, mmax, cnt, Wc2T, bc2, h2, 1);

  // classifier
  k_cls<<<1024, 256, 0, stream>>>(h2, Wf, bf, out);
}

// Round 2
// 794.170 us; speedup vs baseline: 4.4280x; 4.4280x over previous
//
#include <hip/hip_runtime.h>

#define NN 100000
#define NE 1000000
#define FC 64
#define NCLS 32
#define NB 391  // ceil(NN/256)

// ---------- CSR build ----------
__global__ void k_zero_i(int* __restrict__ p, int n){
  int i = blockIdx.x*256 + threadIdx.x;
  if (i < n) p[i] = 0;
}

__global__ void k_deg(const int* __restrict__ dst, int* __restrict__ deg){
  int e = blockIdx.x*256 + threadIdx.x;
  if (e < NE) atomicAdd(&deg[dst[e]], 1);
}

__global__ void k_scan1(const int* __restrict__ deg, int* __restrict__ inc,
                        int* __restrict__ part){
  __shared__ int s[256];
  int tid = threadIdx.x;
  int i = blockIdx.x*256 + tid;
  s[tid] = (i < NN) ? deg[i] : 0;
  __syncthreads();
  for (int off = 1; off < 256; off <<= 1){
    int t = (tid >= off) ? s[tid-off] : 0;
    __syncthreads();
    s[tid] += t;
    __syncthreads();
  }
  inc[i] = s[tid];
  if (tid == 255) part[blockIdx.x] = s[255];
}

__global__ void k_scan2(int* __restrict__ part){
  __shared__ int s[512];
  int tid = threadIdx.x;
  s[tid] = (tid < NB) ? part[tid] : 0;
  __syncthreads();
  for (int off = 1; off < 512; off <<= 1){
    int t = (tid >= off) ? s[tid-off] : 0;
    __syncthreads();
    s[tid] += t;
    __syncthreads();
  }
  if (tid < NB) part[tid] = s[tid];
}

__global__ void k_scan3(const int* __restrict__ inc, const int* __restrict__ part,
                        int* __restrict__ rowptr){
  int i = blockIdx.x*256 + threadIdx.x;
  if (i < NN){
    int base = blockIdx.x ? part[blockIdx.x-1] : 0;
    rowptr[i+1] = inc[i] + base;
  }
  if (i == 0) rowptr[0] = 0;
}

__global__ void k_copy(const int* __restrict__ rowptr, int* __restrict__ cursor){
  int i = blockIdx.x*256 + threadIdx.x;
  if (i < NN) cursor[i] = rowptr[i];
}

__global__ void k_scatter(const int* __restrict__ src, const int* __restrict__ dst,
                          int* __restrict__ cursor, int* __restrict__ srcs){
  int e = blockIdx.x*256 + threadIdx.x;
  if (e < NE){
    int d = dst[e];
    int p = atomicAdd(&cursor[d], 1);
    srcs[p] = src[e];
  }
}

// ---------- fold post+lin: WcT[k][o] = sum_j Wlin[o][j]*Wpost[j][k]; bc = Wlin*bpost + blin ----------
__global__ void k_prep(const float* __restrict__ Wlin, const float* __restrict__ blin,
                       const float* __restrict__ Wpost, const float* __restrict__ bpost,
                       float* __restrict__ WcT, float* __restrict__ bc){
  int t = blockIdx.x*256 + threadIdx.x;
  if (t < 256*FC){
    int k = t >> 6, o = t & 63;
    float s = 0.f;
    #pragma unroll 8
    for (int j = 0; j < 64; j++) s += Wlin[o*64+j] * Wpost[j*256+k];
    WcT[t] = s;                      // t == k*64+o
  }
  if (t < FC){
    float s = blin[t];
    for (int j = 0; j < 64; j++) s += Wlin[t*64+j] * bpost[j];
    bc[t] = s;
  }
}

// ---------- per-node pre-transform: uv[n] = [ u' = WpreL*x + bpre | v = WpreR*x ] ----------
__global__ __launch_bounds__(256, 4) void k_uv(
    const float* __restrict__ xin, const float* __restrict__ Wpre,
    const float* __restrict__ bpre, float* __restrict__ uv){
  __shared__ float WS[64*129];      // WS[k*129 + j]: j<64 -> Wpre[j][k]; j>=64 -> Wpre[j-64][64+k]
  __shared__ float xb[4][64];
  __shared__ float bS[64];
  const int tid = threadIdx.x;
  for (int i = tid; i < 64*128; i += 256){
    int o = i >> 7, kk = i & 127;
    int k = kk & 63, j = (kk < 64) ? o : (64 + o);
    WS[k*129 + j] = Wpre[i];        // global read coalesced; LDS write (k+j)%32 -> 2-way, free
  }
  if (tid < 64) bS[tid] = bpre[tid];
  __syncthreads();

  const int w = tid >> 6, lane = tid & 63;
  const int stride = gridDim.x * 4;
  const int nit = (NN + stride - 1) / stride;
  int node = blockIdx.x*4 + w;
  for (int it = 0; it < nit; it++, node += stride){
    bool act = node < NN;
    if (act) xb[w][lane] = xin[node*64 + lane];
    __syncthreads();
    if (act){
      float acc0 = bS[lane], acc1 = 0.f;
      #pragma unroll 8
      for (int k = 0; k < 64; k++){
        float xv = xb[w][k];                 // broadcast
        acc0 += xv * WS[k*129 + lane];       // (k+lane)%32 -> 2-way, free
        acc1 += xv * WS[k*129 + 64 + lane];
      }
      uv[node*128 + lane]      = acc0;
      uv[node*128 + 64 + lane] = acc1;
    }
    __syncthreads();
  }
}

// ---------- fused CSR aggregation + post GEMM: h = Wc*[x|mean|max|sum] + bc ----------
__global__ __launch_bounds__(512, 4) void k_agg(
    const float* __restrict__ xin, const float* __restrict__ uv,
    const int* __restrict__ rowptr, const int* __restrict__ srcs,
    const float* __restrict__ WcT, const float* __restrict__ bc,
    float* __restrict__ hout, int relu){
  __shared__ float W[256*64];
  __shared__ float zb[8][256];
  __shared__ float bS[64];
  const int tid = threadIdx.x;
  for (int i = tid; i < 256*64; i += 512) W[i] = WcT[i];
  if (tid < 64) bS[tid] = bc[tid];
  __syncthreads();

  const int w = tid >> 6, lane = tid & 63;
  const int stride = gridDim.x * 8;
  const int nit = (NN + stride - 1) / stride;
  int node = blockIdx.x*8 + w;
  for (int it = 0; it < nit; it++, node += stride){
    bool act = node < NN;
    if (act){
      int r0 = rowptr[node], r1 = rowptr[node+1];
      int d = r1 - r0;
      float up = uv[node*128 + lane];        // u' (bias included)
      float xv = xin[node*64 + lane];
      float S = 0.f, M = -3.402823466e+38f;
      int j = r0;
      for (; j + 1 < r1; j += 2){            // coalesced 256B row reads
        int s0 = srcs[j], s1 = srcs[j+1];
        float a0 = uv[s0*128 + 64 + lane];
        float a1 = uv[s1*128 + 64 + lane];
        S += a0 + a1;
        M = fmaxf(M, fmaxf(a0, a1));
      }
      if (j < r1){
        float a0 = uv[srcs[j]*128 + 64 + lane];
        S += a0; M = fmaxf(M, a0);
      }
      float mean, mx, sm;
      if (d > 0){
        float fd = (float)d;
        mean = up + S / fd;
        mx   = up + M;
        sm   = fd * up + S;
      } else { mean = 0.f; mx = 0.f; sm = 0.f; }   // PyG empty-segment semantics
      zb[w][lane]       = xv;
      zb[w][64 + lane]  = mean;
      zb[w][128 + lane] = mx;
      zb[w][192 + lane] = sm;
    }
    __syncthreads();
    if (act){
      float acc = bS[lane];
      #pragma unroll 8
      for (int kb = 0; kb < 64; kb++){
        float4 z = *(const float4*)&zb[w][kb*4];  // broadcast
        const float* wp = &W[kb*4*64 + lane];
        acc += wp[0]*z.x + wp[64]*z.y + wp[128]*z.z + wp[192]*z.w;
      }
      hout[node*64 + lane] = relu ? fmaxf(acc, 0.f) : acc;
    }
    __syncthreads();
  }
}

// ---------- classifier ----------
__global__ __launch_bounds__(256, 2) void k_cls(
    const float* __restrict__ h, const float* __restrict__ Wf,
    const float* __restrict__ bfv, float* __restrict__ out){
  __shared__ float WT[64*NCLS];     // WT[k][c]
  __shared__ float hS[4][2][64];
  __shared__ float bS[NCLS];
  const int tid = threadIdx.x;
  for (int i = tid; i < 64*NCLS; i += 256){
    int k = i >> 5, c = i & 31;
    WT[k*NCLS + c] = Wf[c*64 + k];
  }
  if (tid < NCLS) bS[tid] = bfv[tid];
  __syncthreads();

  const int w = tid >> 6, lane = tid & 63;
  const int half = lane >> 5, c = lane & 31;
  const int npairs = NN / 2;
  const int stride = gridDim.x * 4;
  const int nit = (npairs + stride - 1) / stride;
  int pair = blockIdx.x*4 + w;
  for (int it = 0; it < nit; it++, pair += stride){
    bool act = pair < npairs;
    if (act){
      hS[w][0][lane] = h[(2*pair)  *64 + lane];
      hS[w][1][lane] = h[(2*pair+1)*64 + lane];
    }
    __syncthreads();
    if (act){
      float acc = bS[c];
      #pragma unroll 8
      for (int k = 0; k < 64; k++)
        acc += WT[k*NCLS + c] * hS[w][half][k];
      out[(2*pair + half)*NCLS + c] = acc;
    }
    __syncthreads();
  }
}

extern "C" void kernel_launch(void* const* d_in, const int* in_sizes, int n_in,
                              void* d_out, int out_size, void* d_ws, size_t ws_size,
                              hipStream_t stream){
  const float* x      = (const float*)d_in[0];
  const int*   ei     = (const int*)  d_in[1];
  const int*   src    = ei;
  const int*   dst    = ei + NE;
  const float* W1_pre = (const float*)d_in[2];
  const float* b1_pre = (const float*)d_in[3];
  const float* W1_post= (const float*)d_in[4];
  const float* b1_post= (const float*)d_in[5];
  const float* W1_lin = (const float*)d_in[6];
  const float* b1_lin = (const float*)d_in[7];
  const float* W2_pre = (const float*)d_in[8];
  const float* b2_pre = (const float*)d_in[9];
  const float* W2_post= (const float*)d_in[10];
  const float* b2_post= (const float*)d_in[11];
  const float* W2_lin = (const float*)d_in[12];
  const float* b2_lin = (const float*)d_in[13];
  const float* Wf     = (const float*)d_in[14];
  const float* bf     = (const float*)d_in[15];
  float* out = (float*)d_out;

  size_t off = 0;
  char* ws = (char*)d_ws;
  auto alloc = [&](size_t bytes){ void* p = ws + off; off += (bytes + 255) & ~(size_t)255; return p; };
  int*   deg    = (int*)  alloc(NN*4);
  int*   rowptr = (int*)  alloc((NN+1)*4);
  int*   cursor = (int*)  alloc(NN*4);
  int*   inc    = (int*)  alloc(NB*256*4);
  int*   part   = (int*)  alloc(512*4);
  int*   srcs   = (int*)  alloc((size_t)NE*4);
  float* uv     = (float*)alloc((size_t)NN*128*4);
  float* h1     = (float*)alloc((size_t)NN*64*4);
  float* Wc1T   = (float*)alloc(256*64*4);
  float* bc1    = (float*)alloc(64*4);
  float* Wc2T   = (float*)alloc(256*64*4);
  float* bc2    = (float*)alloc(64*4);
  float* h2;
  if (off + (size_t)NN*64*4 <= ws_size) h2 = (float*)alloc((size_t)NN*64*4);
  else h2 = h1;   // safe alias: k_agg reads only its own xin row before writing it

  // weight folding
  k_prep<<<64, 256, 0, stream>>>(W1_lin, b1_lin, W1_post, b1_post, Wc1T, bc1);
  k_prep<<<64, 256, 0, stream>>>(W2_lin, b2_lin, W2_post, b2_post, Wc2T, bc2);

  // CSR build (once per call; shared by both layers)
  k_zero_i<<<NB, 256, 0, stream>>>(deg, NN);
  k_deg<<<(NE+255)/256, 256, 0, stream>>>(dst, deg);
  k_scan1<<<NB, 256, 0, stream>>>(deg, inc, part);
  k_scan2<<<1, 512, 0, stream>>>(part);
  k_scan3<<<NB, 256, 0, stream>>>(inc, part, rowptr);
  k_copy<<<NB, 256, 0, stream>>>(rowptr, cursor);
  k_scatter<<<(NE+255)/256, 256, 0, stream>>>(src, dst, cursor, srcs);

  // layer 1
  k_uv <<<2048, 256, 0, stream>>>(x, W1_pre, b1_pre, uv);
  k_agg<<<1024, 512, 0, stream>>>(x, uv, rowptr, srcs, Wc1T, bc1, h1, 1);

  // layer 2 (h2 may alias h1 — in-place safe)
  k_uv <<<2048, 256, 0, stream>>>(h1, W2_pre, b2_pre, uv);
  k_agg<<<1024, 512, 0, stream>>>(h1, uv, rowptr, srcs, Wc2T, bc2, h2, 1);

  // classifier
  k_cls<<<1024, 256, 0, stream>>>(h2, Wf, bf, out);
}

// Round 3
// 674.982 us; speedup vs baseline: 5.2099x; 1.1766x over previous
//
#include <hip/hip_runtime.h>

#define NN 100000
#define NE 1000000
#define NCLS 32
#define NB 391  // ceil(NN/256)

__device__ __forceinline__ float rlf(float x, int l){
  return __int_as_float(__builtin_amdgcn_readlane(__float_as_int(x), l));
}

// ---------- CSR build ----------
__global__ void k_zero_i(int* __restrict__ p, int n){
  int i = blockIdx.x*256 + threadIdx.x;
  if (i < n) p[i] = 0;
}

__global__ void k_deg(const int* __restrict__ dst, int* __restrict__ deg){
  int e = blockIdx.x*256 + threadIdx.x;
  if (e < NE) atomicAdd(&deg[dst[e]], 1);
}

__global__ void k_scan1(const int* __restrict__ deg, int* __restrict__ inc,
                        int* __restrict__ part){
  __shared__ int s[256];
  int tid = threadIdx.x;
  int i = blockIdx.x*256 + tid;
  s[tid] = (i < NN) ? deg[i] : 0;
  __syncthreads();
  for (int off = 1; off < 256; off <<= 1){
    int t = (tid >= off) ? s[tid-off] : 0;
    __syncthreads();
    s[tid] += t;
    __syncthreads();
  }
  inc[i] = s[tid];
  if (tid == 255) part[blockIdx.x] = s[255];
}

__global__ void k_scan2(int* __restrict__ part){
  __shared__ int s[512];
  int tid = threadIdx.x;
  s[tid] = (tid < NB) ? part[tid] : 0;
  __syncthreads();
  for (int off = 1; off < 512; off <<= 1){
    int t = (tid >= off) ? s[tid-off] : 0;
    __syncthreads();
    s[tid] += t;
    __syncthreads();
  }
  if (tid < NB) part[tid] = s[tid];
}

__global__ void k_scan3(const int* __restrict__ inc, const int* __restrict__ part,
                        int* __restrict__ rowptr){
  int i = blockIdx.x*256 + threadIdx.x;
  if (i < NN){
    int base = blockIdx.x ? part[blockIdx.x-1] : 0;
    rowptr[i+1] = inc[i] + base;
  }
  if (i == 0) rowptr[0] = 0;
}

__global__ void k_copy(const int* __restrict__ rowptr, int* __restrict__ cursor){
  int i = blockIdx.x*256 + threadIdx.x;
  if (i < NN) cursor[i] = rowptr[i];
}

__global__ void k_scatter(const int* __restrict__ src, const int* __restrict__ dst,
                          int* __restrict__ cursor, int* __restrict__ srcs){
  int e = blockIdx.x*256 + threadIdx.x;
  if (e < NE){
    int d = dst[e];
    int p = atomicAdd(&cursor[d], 1);
    srcs[p] = src[e];
  }
}

// ---------- fold post+lin: WcT[k][o] = sum_j Wlin[o][j]*Wpost[j][k]; bc = Wlin*bpost + blin ----------
__global__ void k_prep(const float* __restrict__ Wlin, const float* __restrict__ blin,
                       const float* __restrict__ Wpost, const float* __restrict__ bpost,
                       float* __restrict__ WcT, float* __restrict__ bc){
  int t = blockIdx.x*256 + threadIdx.x;
  if (t < 256*64){
    int k = t >> 6, o = t & 63;
    float s = 0.f;
    #pragma unroll 8
    for (int j = 0; j < 64; j++) s += Wlin[o*64+j] * Wpost[j*256+k];
    WcT[t] = s;                      // t == k*64+o
  }
  if (t < 64){
    float s = blin[t];
    for (int j = 0; j < 64; j++) s += Wlin[t*64+j] * bpost[j];
    bc[t] = s;
  }
}

// ---------- per-node pre-transform: u = WpreL*x + bpre ; v = WpreR*x ----------
// 4 nodes per wave, x in registers, readlane broadcast, W in LDS.
__global__ __launch_bounds__(512, 2) void k_uv(
    const float* __restrict__ xin, const float* __restrict__ Wpre,
    const float* __restrict__ bpre, float* __restrict__ u, float* __restrict__ v){
  __shared__ float WS[64*128];      // WS[k*128 + half*64 + o] = Wpre[o][half*64 + k]
  __shared__ float bS[64];
  const int tid = threadIdx.x;
  for (int i = tid; i < 64*128; i += 512){
    int o = i >> 7, kk = i & 127;   // Wpre[o][kk]
    int k = kk & 63, half = kk >> 6;
    WS[k*128 + half*64 + o] = Wpre[i];
  }
  if (tid < 64) bS[tid] = bpre[tid];
  __syncthreads();

  const int lane = tid & 63;
  const int wid = blockIdx.x*8 + (tid >> 6);
  const int nwaves = gridDim.x*8;
  const float bias = bS[lane];
  for (int g = wid; g < NN/4; g += nwaves){
    const int n0 = g*4;
    float x0 = xin[(n0+0)*64 + lane];
    float x1 = xin[(n0+1)*64 + lane];
    float x2 = xin[(n0+2)*64 + lane];
    float x3 = xin[(n0+3)*64 + lane];
    float u0=bias,u1=bias,u2=bias,u3=bias;
    float v0=0.f,v1=0.f,v2=0.f,v3=0.f;
    #pragma unroll 4
    for (int k = 0; k < 64; k++){
      float wu = WS[k*128 + lane];
      float wv = WS[k*128 + 64 + lane];
      float a0 = rlf(x0, k), a1 = rlf(x1, k), a2 = rlf(x2, k), a3 = rlf(x3, k);
      u0 = fmaf(a0, wu, u0); v0 = fmaf(a0, wv, v0);
      u1 = fmaf(a1, wu, u1); v1 = fmaf(a1, wv, v1);
      u2 = fmaf(a2, wu, u2); v2 = fmaf(a2, wv, v2);
      u3 = fmaf(a3, wu, u3); v3 = fmaf(a3, wv, v3);
    }
    u[(n0+0)*64+lane] = u0; u[(n0+1)*64+lane] = u1;
    u[(n0+2)*64+lane] = u2; u[(n0+3)*64+lane] = u3;
    v[(n0+0)*64+lane] = v0; v[(n0+1)*64+lane] = v1;
    v[(n0+2)*64+lane] = v2; v[(n0+3)*64+lane] = v3;
  }
}

// ---------- fused CSR gather + post GEMM: h = Wc*[x|mean|max|sum] + bc, relu ----------
// 4 nodes per wave; z in registers; readlane broadcast; W reads amortized over 4 nodes.
// No barriers in the main loop — waves run independently.
__global__ __launch_bounds__(512, 2) void k_agg(
    const float* __restrict__ xin, const float* __restrict__ u,
    const float* __restrict__ v,
    const int* __restrict__ rowptr, const int* __restrict__ srcs,
    const float* __restrict__ WcT, const float* __restrict__ bc,
    float* __restrict__ hout){
  __shared__ float W[256*64];       // [k][o]
  __shared__ float bS[64];
  const int tid = threadIdx.x;
  for (int i = tid; i < 256*64; i += 512) W[i] = WcT[i];
  if (tid < 64) bS[tid] = bc[tid];
  __syncthreads();

  const int lane = tid & 63;
  const int wid = blockIdx.x*8 + (tid >> 6);
  const int nwaves = gridDim.x*8;
  const float bias = bS[lane];
  for (int g = wid; g < NN/4; g += nwaves){
    const int n0 = g*4;
    float z[4][4];                  // [node][quadrant: x|mean|max|sum]
    #pragma unroll
    for (int n = 0; n < 4; n++){
      const int node = n0 + n;
      const int r0 = rowptr[node], r1 = rowptr[node+1];
      float up = u[node*64 + lane];       // issue early
      float xv = xin[node*64 + lane];
      float S = 0.f, M = -3.402823466e+38f;
      int j = r0;
      for (; j + 3 < r1; j += 4){         // 4 independent 256B row loads in flight
        int s0 = srcs[j], s1 = srcs[j+1], s2 = srcs[j+2], s3 = srcs[j+3];
        float a0 = v[s0*64+lane], a1 = v[s1*64+lane];
        float a2 = v[s2*64+lane], a3 = v[s3*64+lane];
        S += (a0 + a1) + (a2 + a3);
        M = fmaxf(M, fmaxf(fmaxf(a0, a1), fmaxf(a2, a3)));
      }
      for (; j < r1; j++){
        float a = v[srcs[j]*64+lane];
        S += a; M = fmaxf(M, a);
      }
      const int d = r1 - r0;
      z[n][0] = xv;
      if (d > 0){
        float fd = (float)d;
        z[n][1] = up + S / fd;
        z[n][2] = up + M;
        z[n][3] = fd*up + S;
      } else {
        z[n][1] = 0.f; z[n][2] = 0.f; z[n][3] = 0.f;   // PyG empty-segment semantics
      }
    }
    float acc0 = bias, acc1 = bias, acc2 = bias, acc3 = bias;
    #pragma unroll
    for (int q = 0; q < 4; q++){
      const float* Wq = &W[q*64*64];
      #pragma unroll 4
      for (int k = 0; k < 64; k++){       // adjacent wv offsets merge to ds_read2_b32
        float wv = Wq[k*64 + lane];
        float a0 = rlf(z[0][q], k), a1 = rlf(z[1][q], k);
        float a2 = rlf(z[2][q], k), a3 = rlf(z[3][q], k);
        acc0 = fmaf(a0, wv, acc0); acc1 = fmaf(a1, wv, acc1);
        acc2 = fmaf(a2, wv, acc2); acc3 = fmaf(a3, wv, acc3);
      }
    }
    hout[(n0+0)*64+lane] = fmaxf(acc0, 0.f);
    hout[(n0+1)*64+lane] = fmaxf(acc1, 0.f);
    hout[(n0+2)*64+lane] = fmaxf(acc2, 0.f);
    hout[(n0+3)*64+lane] = fmaxf(acc3, 0.f);
  }
}

// ---------- classifier: 8 nodes per wave (4 pairs), h rows in registers ----------
__global__ __launch_bounds__(512, 2) void k_cls(
    const float* __restrict__ h, const float* __restrict__ Wf,
    const float* __restrict__ bfv, float* __restrict__ out){
  __shared__ float WT[64*NCLS];     // WT[k*32 + c] = Wf[c*64+k]
  __shared__ float bS[NCLS];
  const int tid = threadIdx.x;
  for (int i = tid; i < 64*NCLS; i += 512){
    int k = i >> 5, c = i & 31;
    WT[k*NCLS + c] = Wf[c*64 + k];
  }
  if (tid < NCLS) bS[tid] = bfv[tid];
  __syncthreads();

  const int lane = tid & 63;
  const int wid = blockIdx.x*8 + (tid >> 6);
  const int nwaves = gridDim.x*8;
  const int c = lane & 31;
  const bool hi = lane >= 32;
  const float bias = bS[c];
  for (int g = wid; g < NN/8; g += nwaves){
    const int n0 = g*8;
    float h0 = h[(n0+0)*64+lane], h1 = h[(n0+1)*64+lane];
    float h2 = h[(n0+2)*64+lane], h3 = h[(n0+3)*64+lane];
    float h4 = h[(n0+4)*64+lane], h5 = h[(n0+5)*64+lane];
    float h6 = h[(n0+6)*64+lane], h7 = h[(n0+7)*64+lane];
    float acc0 = bias, acc1 = bias, acc2 = bias, acc3 = bias;
    #pragma unroll 4
    for (int k = 0; k < 64; k++){
      float wv = WT[k*NCLS + c];
      float e0 = rlf(h0,k), e1 = rlf(h1,k), e2 = rlf(h2,k), e3 = rlf(h3,k);
      float e4 = rlf(h4,k), e5 = rlf(h5,k), e6 = rlf(h6,k), e7 = rlf(h7,k);
      acc0 = fmaf(hi ? e1 : e0, wv, acc0);
      acc1 = fmaf(hi ? e3 : e2, wv, acc1);
      acc2 = fmaf(hi ? e5 : e4, wv, acc2);
      acc3 = fmaf(hi ? e7 : e6, wv, acc3);
    }
    out[n0*NCLS +   0 + lane] = acc0;   // = out[(n0+0+hi)*32 + c]
    out[n0*NCLS +  64 + lane] = acc1;
    out[n0*NCLS + 128 + lane] = acc2;
    out[n0*NCLS + 192 + lane] = acc3;
  }
}

extern "C" void kernel_launch(void* const* d_in, const int* in_sizes, int n_in,
                              void* d_out, int out_size, void* d_ws, size_t ws_size,
                              hipStream_t stream){
  const float* x      = (const float*)d_in[0];
  const int*   ei     = (const int*)  d_in[1];
  const int*   src    = ei;
  const int*   dst    = ei + NE;
  const float* W1_pre = (const float*)d_in[2];
  const float* b1_pre = (const float*)d_in[3];
  const float* W1_post= (const float*)d_in[4];
  const float* b1_post= (const float*)d_in[5];
  const float* W1_lin = (const float*)d_in[6];
  const float* b1_lin = (const float*)d_in[7];
  const float* W2_pre = (const float*)d_in[8];
  const float* b2_pre = (const float*)d_in[9];
  const float* W2_post= (const float*)d_in[10];
  const float* b2_post= (const float*)d_in[11];
  const float* W2_lin = (const float*)d_in[12];
  const float* b2_lin = (const float*)d_in[13];
  const float* Wf     = (const float*)d_in[14];
  const float* bf     = (const float*)d_in[15];
  float* out = (float*)d_out;

  size_t off = 0;
  char* ws = (char*)d_ws;
  auto alloc = [&](size_t bytes){ void* p = ws + off; off += (bytes + 255) & ~(size_t)255; return p; };
  int*   deg    = (int*)  alloc(NN*4);
  int*   rowptr = (int*)  alloc((NN+1)*4);
  int*   cursor = (int*)  alloc(NN*4);
  int*   inc    = (int*)  alloc(NB*256*4);
  int*   part   = (int*)  alloc(512*4);
  int*   srcs   = (int*)  alloc((size_t)NE*4);
  float* u      = (float*)alloc((size_t)NN*64*4);
  float* v      = (float*)alloc((size_t)NN*64*4);
  float* h1     = (float*)alloc((size_t)NN*64*4);
  float* Wc1T   = (float*)alloc(256*64*4);
  float* bc1    = (float*)alloc(64*4);
  float* Wc2T   = (float*)alloc(256*64*4);
  float* bc2    = (float*)alloc(64*4);
  float* h2;
  if (off + (size_t)NN*64*4 <= ws_size) h2 = (float*)alloc((size_t)NN*64*4);
  else h2 = h1;   // safe alias: layer-2 k_agg reads xin only at its own row before writing it

  // weight folding
  k_prep<<<64, 256, 0, stream>>>(W1_lin, b1_lin, W1_post, b1_post, Wc1T, bc1);
  k_prep<<<64, 256, 0, stream>>>(W2_lin, b2_lin, W2_post, b2_post, Wc2T, bc2);

  // CSR build (shared by both layers)
  k_zero_i<<<NB, 256, 0, stream>>>(deg, NN);
  k_deg<<<(NE+255)/256, 256, 0, stream>>>(dst, deg);
  k_scan1<<<NB, 256, 0, stream>>>(deg, inc, part);
  k_scan2<<<1, 512, 0, stream>>>(part);
  k_scan3<<<NB, 256, 0, stream>>>(inc, part, rowptr);
  k_copy<<<NB, 256, 0, stream>>>(rowptr, cursor);
  k_scatter<<<(NE+255)/256, 256, 0, stream>>>(src, dst, cursor, srcs);

  // layer 1
  k_uv <<<1024, 512, 0, stream>>>(x, W1_pre, b1_pre, u, v);
  k_agg<<<512, 512, 0, stream>>>(x, u, v, rowptr, srcs, Wc1T, bc1, h1);

  // layer 2 (h2 may alias h1 — in-place safe)
  k_uv <<<1024, 512, 0, stream>>>(h1, W2_pre, b2_pre, u, v);
  k_agg<<<512, 512, 0, stream>>>(h1, u, v, rowptr, srcs, Wc2T, bc2, h2);

  // classifier
  k_cls<<<512, 512, 0, stream>>>(h2, Wf, bf, out);
}

// Round 4
// 644.477 us; speedup vs baseline: 5.4565x; 1.0473x over previous
//
#include <hip/hip_runtime.h>

#define NN 100000
#define NE 1000000
#define NCLS 32
#define NB 391  // ceil(NN/256)
#define GN 32   // nodes per k_agg group

typedef __bf16 bf16x8 __attribute__((ext_vector_type(8)));
typedef float f32x16 __attribute__((ext_vector_type(16)));

__device__ __forceinline__ float rlf(float x, int l){
  return __int_as_float(__builtin_amdgcn_readlane(__float_as_int(x), l));
}

// pack hi16 of two f32 into one u32: {hi16(f1) : hi16(f0)}  (f0 -> low half)
__device__ __forceinline__ unsigned pk_hi(unsigned u1, unsigned u0){
  return __builtin_amdgcn_perm(u1, u0, 0x07060302u);
}

__device__ __forceinline__ f32x16 mfma_b(uint4 a, uint4 b, f32x16 c){
  bf16x8 av, bv;
  __builtin_memcpy(&av, &a, 16);
  __builtin_memcpy(&bv, &b, 16);
  return __builtin_amdgcn_mfma_f32_32x32x16_bf16(av, bv, c, 0, 0, 0);
}

// ---------- CSR build ----------
__global__ void k_zero_i(int* __restrict__ p, int n){
  int i = blockIdx.x*256 + threadIdx.x;
  if (i < n) p[i] = 0;
}

__global__ void k_deg(const int* __restrict__ dst, int* __restrict__ deg){
  int e = blockIdx.x*256 + threadIdx.x;
  if (e < NE) atomicAdd(&deg[dst[e]], 1);
}

__global__ void k_scan1(const int* __restrict__ deg, int* __restrict__ inc,
                        int* __restrict__ part){
  __shared__ int s[256];
  int tid = threadIdx.x;
  int i = blockIdx.x*256 + tid;
  s[tid] = (i < NN) ? deg[i] : 0;
  __syncthreads();
  for (int off = 1; off < 256; off <<= 1){
    int t = (tid >= off) ? s[tid-off] : 0;
    __syncthreads();
    s[tid] += t;
    __syncthreads();
  }
  inc[i] = s[tid];
  if (tid == 255) part[blockIdx.x] = s[255];
}

__global__ void k_scan2(int* __restrict__ part){
  __shared__ int s[512];
  int tid = threadIdx.x;
  s[tid] = (tid < NB) ? part[tid] : 0;
  __syncthreads();
  for (int off = 1; off < 512; off <<= 1){
    int t = (tid >= off) ? s[tid-off] : 0;
    __syncthreads();
    s[tid] += t;
    __syncthreads();
  }
  if (tid < NB) part[tid] = s[tid];
}

__global__ void k_scan3(const int* __restrict__ inc, const int* __restrict__ part,
                        int* __restrict__ rowptr){
  int i = blockIdx.x*256 + threadIdx.x;
  if (i < NN){
    int base = blockIdx.x ? part[blockIdx.x-1] : 0;
    rowptr[i+1] = inc[i] + base;
  }
  if (i == 0) rowptr[0] = 0;
}

__global__ void k_copy(const int* __restrict__ rowptr, int* __restrict__ cursor){
  int i = blockIdx.x*256 + threadIdx.x;
  if (i < NN) cursor[i] = rowptr[i];
}

__global__ void k_scatter(const int* __restrict__ src, const int* __restrict__ dst,
                          int* __restrict__ cursor, int* __restrict__ srcs){
  int e = blockIdx.x*256 + threadIdx.x;
  if (e < NE){
    int d = dst[e];
    int p = atomicAdd(&cursor[d], 1);
    srcs[p] = src[e];
  }
}

// ---------- fold post+lin: WcT[k][o] = sum_j Wlin[o][j]*Wpost[j][k]; bc = Wlin*bpost + blin ----------
__global__ void k_prep(const float* __restrict__ Wlin, const float* __restrict__ blin,
                       const float* __restrict__ Wpost, const float* __restrict__ bpost,
                       float* __restrict__ WcT, float* __restrict__ bc){
  int t = blockIdx.x*256 + threadIdx.x;
  if (t < 256*64){
    int k = t >> 6, o = t & 63;
    float s = 0.f;
    #pragma unroll 8
    for (int j = 0; j < 64; j++) s += Wlin[o*64+j] * Wpost[j*256+k];
    WcT[t] = s;                      // t == k*64+o
  }
  if (t < 64){
    float s = blin[t];
    for (int j = 0; j < 64; j++) s += Wlin[t*64+j] * bpost[j];
    bc[t] = s;
  }
}

// ---------- emit W in MFMA B-fragment order, split-bf16 ----------
// Wfrag[wreg][step][lane] : wreg = {s=hi/lo}<<1 | {ntile}; 4096 uint4 total
__global__ void k_wfrag(const float* __restrict__ WcT, uint4* __restrict__ Wfrag){
  int idx = blockIdx.x*256 + threadIdx.x;
  if (idx >= 4096) return;
  int lane = idx & 63;
  int step = (idx >> 6) & 15;
  int wreg = idx >> 10;
  int s = wreg >> 1, t = wreg & 1;
  int col = t*32 + (lane & 31);
  unsigned o[4];
  #pragma unroll
  for (int p = 0; p < 4; p++){
    int k0 = step*16 + ((lane>>5)*8) + 2*p;
    float f0 = WcT[k0*64 + col], f1 = WcT[(k0+1)*64 + col];
    unsigned u0 = __float_as_uint(f0), u1 = __float_as_uint(f1);
    if (s == 0){
      o[p] = pk_hi(u1, u0);
    } else {
      float r0 = f0 - __uint_as_float(u0 & 0xFFFF0000u);
      float r1 = f1 - __uint_as_float(u1 & 0xFFFF0000u);
      o[p] = pk_hi(__float_as_uint(r1), __float_as_uint(r0));
    }
  }
  Wfrag[idx] = make_uint4(o[0], o[1], o[2], o[3]);
}

// ---------- per-node pre-transform: u = WpreL*x + bpre ; v = WpreR*x ----------
__global__ __launch_bounds__(512, 2) void k_uv(
    const float* __restrict__ xin, const float* __restrict__ Wpre,
    const float* __restrict__ bpre, float* __restrict__ u, float* __restrict__ v){
  __shared__ float WS[64*128];      // WS[k*128 + half*64 + o] = Wpre[o][half*64 + k]
  __shared__ float bS[64];
  const int tid = threadIdx.x;
  for (int i = tid; i < 64*128; i += 512){
    int o = i >> 7, kk = i & 127;   // Wpre[o][kk]
    int k = kk & 63, half = kk >> 6;
    WS[k*128 + half*64 + o] = Wpre[i];
  }
  if (tid < 64) bS[tid] = bpre[tid];
  __syncthreads();

  const int lane = tid & 63;
  const int wid = blockIdx.x*8 + (tid >> 6);
  const int nwaves = gridDim.x*8;
  const float bias = bS[lane];
  for (int g = wid; g < NN/4; g += nwaves){
    const int n0 = g*4;
    float x0 = xin[(n0+0)*64 + lane];
    float x1 = xin[(n0+1)*64 + lane];
    float x2 = xin[(n0+2)*64 + lane];
    float x3 = xin[(n0+3)*64 + lane];
    float u0=bias,u1=bias,u2=bias,u3=bias;
    float v0=0.f,v1=0.f,v2=0.f,v3=0.f;
    #pragma unroll 4
    for (int k = 0; k < 64; k++){
      float wu = WS[k*128 + lane];
      float wv = WS[k*128 + 64 + lane];
      float a0 = rlf(x0, k), a1 = rlf(x1, k), a2 = rlf(x2, k), a3 = rlf(x3, k);
      u0 = fmaf(a0, wu, u0); v0 = fmaf(a0, wv, v0);
      u1 = fmaf(a1, wu, u1); v1 = fmaf(a1, wv, v1);
      u2 = fmaf(a2, wu, u2); v2 = fmaf(a2, wv, v2);
      u3 = fmaf(a3, wu, u3); v3 = fmaf(a3, wv, v3);
    }
    u[(n0+0)*64+lane] = u0; u[(n0+1)*64+lane] = u1;
    u[(n0+2)*64+lane] = u2; u[(n0+3)*64+lane] = u3;
    v[(n0+0)*64+lane] = v0; v[(n0+1)*64+lane] = v1;
    v[(n0+2)*64+lane] = v2; v[(n0+3)*64+lane] = v3;
  }
}

// ---------- fused CSR gather + MFMA post GEMM ----------
// Block = 4 waves, 32-node group. Gather -> zf(LDS,f32) -> split-bf16 planes ->
// MFMA: wave w owns (split=w>>1, ntile=w&1); lo-split partials via LDS.
__global__ __launch_bounds__(256) void k_agg(
    const float* __restrict__ xin, const float* __restrict__ u,
    const float* __restrict__ v,
    const int* __restrict__ rowptr, const int* __restrict__ srcs,
    const uint4* __restrict__ Wfrag, const float* __restrict__ bc,
    float* __restrict__ hout){
  __shared__ __align__(16) float    zf[GN*260];     // z (f32); later reused for partials
  __shared__ __align__(16) unsigned Zh[GN*132];     // packed bf16-hi pairs
  __shared__ __align__(16) unsigned Zl[GN*132];     // packed bf16-lo pairs
  const int tid = threadIdx.x;
  const int lane = tid & 63;
  const int w = tid >> 6;

  // resident B-fragments: wave w -> (split w>>1, ntile w&1), 16 K-steps
  uint4 wf[16];
  {
    const uint4* base = Wfrag + w*16*64;
    #pragma unroll
    for (int s = 0; s < 16; s++) wf[s] = base[s*64 + lane];
  }
  const float bias = bc[(w&1)*32 + (lane&31)];

  for (int g = blockIdx.x; g < NN/GN; g += gridDim.x){
    const int n0 = g*GN;
    __syncthreads();                 // prior group's partial reads done
    // ---- gather: wave w -> nodes n0 + w*8 .. +8
    for (int nn = 0; nn < 8; nn++){
      const int node = n0 + w*8 + nn;
      const int r0 = rowptr[node], r1 = rowptr[node+1];
      float up = u[node*64 + lane];
      float xv = xin[node*64 + lane];
      float S = 0.f, M = -3.402823466e+38f;
      int j = r0;
      for (; j + 3 < r1; j += 4){
        int s0 = srcs[j], s1 = srcs[j+1], s2 = srcs[j+2], s3 = srcs[j+3];
        float a0 = v[s0*64+lane], a1 = v[s1*64+lane];
        float a2 = v[s2*64+lane], a3 = v[s3*64+lane];
        S += (a0 + a1) + (a2 + a3);
        M = fmaxf(M, fmaxf(fmaxf(a0, a1), fmaxf(a2, a3)));
      }
      for (; j < r1; j++){
        float a = v[srcs[j]*64+lane];
        S += a; M = fmaxf(M, a);
      }
      const int d = r1 - r0;
      float z1, z2, z3;
      if (d > 0){
        float fd = (float)d;
        z1 = up + S / fd;
        z2 = up + M;
        z3 = fd*up + S;
      } else { z1 = 0.f; z2 = 0.f; z3 = 0.f; }
      const int lr = w*8 + nn;
      zf[lr*260 +       lane] = xv;
      zf[lr*260 +  64 + lane] = z1;
      zf[lr*260 + 128 + lane] = z2;
      zf[lr*260 + 192 + lane] = z3;
    }
    __syncthreads();
    // ---- convert: thread (row = tid&31, k-pair block = tid>>5)
    {
      const int n = tid & 31, kb = tid >> 5;
      const float* zr = &zf[n*260 + kb*32];
      unsigned* zh = &Zh[n*132 + kb*16];
      unsigned* zl = &Zl[n*132 + kb*16];
      #pragma unroll
      for (int i = 0; i < 16; i++){
        float f0 = zr[2*i], f1 = zr[2*i+1];
        unsigned u0 = __float_as_uint(f0), u1 = __float_as_uint(f1);
        zh[i] = pk_hi(u1, u0);
        float r0 = f0 - __uint_as_float(u0 & 0xFFFF0000u);
        float r1 = f1 - __uint_as_float(u1 & 0xFFFF0000u);
        zl[i] = pk_hi(__float_as_uint(r1), __float_as_uint(r0));
      }
    }
    __syncthreads();
    // ---- MFMA: A-frag = 16B at [row = lane&31][dword s*8 + (lane>>5)*4]
    f32x16 acc = {};
    const int arow = (lane & 31)*132 + ((lane >> 5) << 2);
    if (w < 2){
      #pragma unroll
      for (int s = 0; s < 16; s++){
        uint4 a = *(const uint4*)&Zh[arow + s*8];
        acc = mfma_b(a, wf[s], acc);
      }
      #pragma unroll
      for (int s = 0; s < 16; s++){
        uint4 a = *(const uint4*)&Zl[arow + s*8];
        acc = mfma_b(a, wf[s], acc);
      }
    } else {
      #pragma unroll
      for (int s = 0; s < 16; s++){
        uint4 a = *(const uint4*)&Zh[arow + s*8];
        acc = mfma_b(a, wf[s], acc);
      }
      float* pw = &zf[(w-2)*1024 + lane*16];
      #pragma unroll
      for (int r = 0; r < 16; r++) pw[r] = acc[r];
    }
    __syncthreads();
    if (w < 2){
      const float* pw = &zf[w*1024 + lane*16];
      #pragma unroll
      for (int r = 0; r < 16; r++){
        float val = fmaxf(acc[r] + pw[r] + bias, 0.f);
        int row = (r & 3) + 8*(r >> 2) + 4*(lane >> 5);   // verified C/D layout
        hout[(size_t)(n0 + row)*64 + (w&1)*32 + (lane & 31)] = val;
      }
    }
  }
}

// ---------- classifier: 8 nodes per wave (4 pairs), h rows in registers ----------
__global__ __launch_bounds__(512, 2) void k_cls(
    const float* __restrict__ h, const float* __restrict__ Wf,
    const float* __restrict__ bfv, float* __restrict__ out){
  __shared__ float WT[64*NCLS];     // WT[k*32 + c] = Wf[c*64+k]
  __shared__ float bS[NCLS];
  const int tid = threadIdx.x;
  for (int i = tid; i < 64*NCLS; i += 512){
    int k = i >> 5, c = i & 31;
    WT[k*NCLS + c] = Wf[c*64 + k];
  }
  if (tid < NCLS) bS[tid] = bfv[tid];
  __syncthreads();

  const int lane = tid & 63;
  const int wid = blockIdx.x*8 + (tid >> 6);
  const int nwaves = gridDim.x*8;
  const int c = lane & 31;
  const bool hi = lane >= 32;
  const float bias = bS[c];
  for (int g = wid; g < NN/8; g += nwaves){
    const int n0 = g*8;
    float h0 = h[(n0+0)*64+lane], h1 = h[(n0+1)*64+lane];
    float h2 = h[(n0+2)*64+lane], h3 = h[(n0+3)*64+lane];
    float h4 = h[(n0+4)*64+lane], h5 = h[(n0+5)*64+lane];
    float h6 = h[(n0+6)*64+lane], h7 = h[(n0+7)*64+lane];
    float acc0 = bias, acc1 = bias, acc2 = bias, acc3 = bias;
    #pragma unroll 4
    for (int k = 0; k < 64; k++){
      float wv = WT[k*NCLS + c];
      float e0 = rlf(h0,k), e1 = rlf(h1,k), e2 = rlf(h2,k), e3 = rlf(h3,k);
      float e4 = rlf(h4,k), e5 = rlf(h5,k), e6 = rlf(h6,k), e7 = rlf(h7,k);
      acc0 = fmaf(hi ? e1 : e0, wv, acc0);
      acc1 = fmaf(hi ? e3 : e2, wv, acc1);
      acc2 = fmaf(hi ? e5 : e4, wv, acc2);
      acc3 = fmaf(hi ? e7 : e6, wv, acc3);
    }
    out[n0*NCLS +   0 + lane] = acc0;
    out[n0*NCLS +  64 + lane] = acc1;
    out[n0*NCLS + 128 + lane] = acc2;
    out[n0*NCLS + 192 + lane] = acc3;
  }
}

extern "C" void kernel_launch(void* const* d_in, const int* in_sizes, int n_in,
                              void* d_out, int out_size, void* d_ws, size_t ws_size,
                              hipStream_t stream){
  const float* x      = (const float*)d_in[0];
  const int*   ei     = (const int*)  d_in[1];
  const int*   src    = ei;
  const int*   dst    = ei + NE;
  const float* W1_pre = (const float*)d_in[2];
  const float* b1_pre = (const float*)d_in[3];
  const float* W1_post= (const float*)d_in[4];
  const float* b1_post= (const float*)d_in[5];
  const float* W1_lin = (const float*)d_in[6];
  const float* b1_lin = (const float*)d_in[7];
  const float* W2_pre = (const float*)d_in[8];
  const float* b2_pre = (const float*)d_in[9];
  const float* W2_post= (const float*)d_in[10];
  const float* b2_post= (const float*)d_in[11];
  const float* W2_lin = (const float*)d_in[12];
  const float* b2_lin = (const float*)d_in[13];
  const float* Wf     = (const float*)d_in[14];
  const float* bf     = (const float*)d_in[15];
  float* out = (float*)d_out;

  size_t off = 0;
  char* ws = (char*)d_ws;
  auto alloc = [&](size_t bytes){ void* p = ws + off; off += (bytes + 255) & ~(size_t)255; return p; };
  int*   deg    = (int*)  alloc(NN*4);
  int*   rowptr = (int*)  alloc((NN+1)*4);
  int*   cursor = (int*)  alloc(NN*4);
  int*   inc    = (int*)  alloc(NB*256*4);
  int*   part   = (int*)  alloc(512*4);
  int*   srcs   = (int*)  alloc((size_t)NE*4);
  float* u      = (float*)alloc((size_t)NN*64*4);
  float* v      = (float*)alloc((size_t)NN*64*4);
  float* h1     = (float*)alloc((size_t)NN*64*4);
  float* Wc1T   = (float*)alloc(256*64*4);
  float* bc1    = (float*)alloc(64*4);
  float* Wc2T   = (float*)alloc(256*64*4);
  float* bc2    = (float*)alloc(64*4);
  uint4* Wfrag1 = (uint4*)alloc(4096*16);
  uint4* Wfrag2 = (uint4*)alloc(4096*16);
  float* h2;
  if (off + (size_t)NN*64*4 <= ws_size) h2 = (float*)alloc((size_t)NN*64*4);
  else h2 = h1;   // safe alias: layer-2 k_agg reads xin only at its own rows before writing them

  // weight folding + fragment emission
  k_prep<<<64, 256, 0, stream>>>(W1_lin, b1_lin, W1_post, b1_post, Wc1T, bc1);
  k_prep<<<64, 256, 0, stream>>>(W2_lin, b2_lin, W2_post, b2_post, Wc2T, bc2);
  k_wfrag<<<16, 256, 0, stream>>>(Wc1T, Wfrag1);
  k_wfrag<<<16, 256, 0, stream>>>(Wc2T, Wfrag2);

  // CSR build (shared by both layers)
  k_zero_i<<<NB, 256, 0, stream>>>(deg, NN);
  k_deg<<<(NE+255)/256, 256, 0, stream>>>(dst, deg);
  k_scan1<<<NB, 256, 0, stream>>>(deg, inc, part);
  k_scan2<<<1, 512, 0, stream>>>(part);
  k_scan3<<<NB, 256, 0, stream>>>(inc, part, rowptr);
  k_copy<<<NB, 256, 0, stream>>>(rowptr, cursor);
  k_scatter<<<(NE+255)/256, 256, 0, stream>>>(src, dst, cursor, srcs);

  // layer 1
  k_uv <<<1024, 512, 0, stream>>>(x, W1_pre, b1_pre, u, v);
  k_agg<<<1024, 256, 0, stream>>>(x, u, v, rowptr, srcs, Wfrag1, bc1, h1);

  // layer 2 (h2 may alias h1 — in-place safe)
  k_uv <<<1024, 512, 0, stream>>>(h1, W2_pre, b2_pre, u, v);
  k_agg<<<1024, 256, 0, stream>>>(h1, u, v, rowptr, srcs, Wfrag2, bc2, h2);

  // classifier
  k_cls<<<512, 512, 0, stream>>>(h2, Wf, bf, out);
}

// Round 5
// 503.717 us; speedup vs baseline: 6.9813x; 1.2794x over previous
//
#include <hip/hip_runtime.h>

#define NN 100000
#define NE 1000000
#define NCLS 32
#define NB 391  // ceil(NN/256)
#define GN 32   // nodes per k_agg group

typedef __bf16 bf16x8 __attribute__((ext_vector_type(8)));
typedef float f32x16 __attribute__((ext_vector_type(16)));

__device__ __forceinline__ float rlf(float x, int l){
  return __int_as_float(__builtin_amdgcn_readlane(__float_as_int(x), l));
}

// pack hi16 of two f32 into one u32: {hi16(f1) : hi16(f0)}  (f0 -> low half)
__device__ __forceinline__ unsigned pk_hi(unsigned u1, unsigned u0){
  return __builtin_amdgcn_perm(u1, u0, 0x07060302u);
}

__device__ __forceinline__ f32x16 mfma_b(uint4 a, uint4 b, f32x16 c){
  bf16x8 av, bv;
  __builtin_memcpy(&av, &a, 16);
  __builtin_memcpy(&bv, &b, 16);
  return __builtin_amdgcn_mfma_f32_32x32x16_bf16(av, bv, c, 0, 0, 0);
}

// ---------- CSR build ----------
__global__ void k_zero_i(int* __restrict__ p, int n){
  int i = blockIdx.x*256 + threadIdx.x;
  if (i < n) p[i] = 0;
}

__global__ void k_deg(const int* __restrict__ dst, int* __restrict__ deg){
  int e = blockIdx.x*256 + threadIdx.x;
  if (e < NE) atomicAdd(&deg[dst[e]], 1);
}

__global__ void k_scan1(const int* __restrict__ deg, int* __restrict__ inc,
                        int* __restrict__ part){
  __shared__ int s[256];
  int tid = threadIdx.x;
  int i = blockIdx.x*256 + tid;
  s[tid] = (i < NN) ? deg[i] : 0;
  __syncthreads();
  for (int off = 1; off < 256; off <<= 1){
    int t = (tid >= off) ? s[tid-off] : 0;
    __syncthreads();
    s[tid] += t;
    __syncthreads();
  }
  inc[i] = s[tid];
  if (tid == 255) part[blockIdx.x] = s[255];
}

__global__ void k_scan2(int* __restrict__ part){
  __shared__ int s[512];
  int tid = threadIdx.x;
  s[tid] = (tid < NB) ? part[tid] : 0;
  __syncthreads();
  for (int off = 1; off < 512; off <<= 1){
    int t = (tid >= off) ? s[tid-off] : 0;
    __syncthreads();
    s[tid] += t;
    __syncthreads();
  }
  if (tid < NB) part[tid] = s[tid];
}

// rowptr[i+1] = inclusive; cursor[i] = exclusive = inclusive - deg[i]
__global__ void k_scan3(const int* __restrict__ inc, const int* __restrict__ part,
                        const int* __restrict__ deg,
                        int* __restrict__ rowptr, int* __restrict__ cursor){
  int i = blockIdx.x*256 + threadIdx.x;
  if (i < NN){
    int base = blockIdx.x ? part[blockIdx.x-1] : 0;
    int inclusive = inc[i] + base;
    rowptr[i+1] = inclusive;
    cursor[i] = inclusive - deg[i];
  }
  if (i == 0) rowptr[0] = 0;
}

__global__ void k_scatter(const int* __restrict__ src, const int* __restrict__ dst,
                          int* __restrict__ cursor, int* __restrict__ srcs){
  int e = blockIdx.x*256 + threadIdx.x;
  if (e < NE){
    int d = dst[e];
    int p = atomicAdd(&cursor[d], 1);
    srcs[p] = src[e];
  }
}

// ---------- fold post+lin: WcT[k][o] = sum_j Wlin[o][j]*Wpost[j][k]; bc = Wlin*bpost + blin ----------
__global__ void k_prep(const float* __restrict__ Wlin, const float* __restrict__ blin,
                       const float* __restrict__ Wpost, const float* __restrict__ bpost,
                       float* __restrict__ WcT, float* __restrict__ bc){
  int t = blockIdx.x*256 + threadIdx.x;
  if (t < 256*64){
    int k = t >> 6, o = t & 63;
    float s = 0.f;
    #pragma unroll 8
    for (int j = 0; j < 64; j++) s += Wlin[o*64+j] * Wpost[j*256+k];
    WcT[t] = s;                      // t == k*64+o
  }
  if (t < 64){
    float s = blin[t];
    for (int j = 0; j < 64; j++) s += Wlin[t*64+j] * bpost[j];
    bc[t] = s;
  }
}

// ---------- emit W in MFMA B-fragment order, split-bf16 ----------
// Wfrag[wreg][step][lane] : wreg = {s=hi/lo}<<1 | {ntile}; 4096 uint4 total
__global__ void k_wfrag(const float* __restrict__ WcT, uint4* __restrict__ Wfrag){
  int idx = blockIdx.x*256 + threadIdx.x;
  if (idx >= 4096) return;
  int lane = idx & 63;
  int step = (idx >> 6) & 15;
  int wreg = idx >> 10;
  int s = wreg >> 1, t = wreg & 1;
  int col = t*32 + (lane & 31);
  unsigned o[4];
  #pragma unroll
  for (int p = 0; p < 4; p++){
    int k0 = step*16 + ((lane>>5)*8) + 2*p;
    float f0 = WcT[k0*64 + col], f1 = WcT[(k0+1)*64 + col];
    unsigned u0 = __float_as_uint(f0), u1 = __float_as_uint(f1);
    if (s == 0){
      o[p] = pk_hi(u1, u0);
    } else {
      float r0 = f0 - __uint_as_float(u0 & 0xFFFF0000u);
      float r1 = f1 - __uint_as_float(u1 & 0xFFFF0000u);
      o[p] = pk_hi(__float_as_uint(r1), __float_as_uint(r0));
    }
  }
  Wfrag[idx] = make_uint4(o[0], o[1], o[2], o[3]);
}

// ---------- per-node pre-transform: u = WpreL*x + bpre ; v = WpreR*x ----------
__global__ __launch_bounds__(512, 2) void k_uv(
    const float* __restrict__ xin, const float* __restrict__ Wpre,
    const float* __restrict__ bpre, float* __restrict__ u, float* __restrict__ v){
  __shared__ float WS[64*128];      // WS[k*128 + half*64 + o] = Wpre[o][half*64 + k]
  __shared__ float bS[64];
  const int tid = threadIdx.x;
  for (int i = tid; i < 64*128; i += 512){
    int o = i >> 7, kk = i & 127;   // Wpre[o][kk]
    int k = kk & 63, half = kk >> 6;
    WS[k*128 + half*64 + o] = Wpre[i];
  }
  if (tid < 64) bS[tid] = bpre[tid];
  __syncthreads();

  const int lane = tid & 63;
  const int wid = blockIdx.x*8 + (tid >> 6);
  const int nwaves = gridDim.x*8;
  const float bias = bS[lane];
  for (int g = wid; g < NN/4; g += nwaves){
    const int n0 = g*4;
    float x0 = xin[(n0+0)*64 + lane];
    float x1 = xin[(n0+1)*64 + lane];
    float x2 = xin[(n0+2)*64 + lane];
    float x3 = xin[(n0+3)*64 + lane];
    float u0=bias,u1=bias,u2=bias,u3=bias;
    float v0=0.f,v1=0.f,v2=0.f,v3=0.f;
    #pragma unroll 4
    for (int k = 0; k < 64; k++){
      float wu = WS[k*128 + lane];
      float wv = WS[k*128 + 64 + lane];
      float a0 = rlf(x0, k), a1 = rlf(x1, k), a2 = rlf(x2, k), a3 = rlf(x3, k);
      u0 = fmaf(a0, wu, u0); v0 = fmaf(a0, wv, v0);
      u1 = fmaf(a1, wu, u1); v1 = fmaf(a1, wv, v1);
      u2 = fmaf(a2, wu, u2); v2 = fmaf(a2, wv, v2);
      u3 = fmaf(a3, wu, u3); v3 = fmaf(a3, wv, v3);
    }
    u[(n0+0)*64+lane] = u0; u[(n0+1)*64+lane] = u1;
    u[(n0+2)*64+lane] = u2; u[(n0+3)*64+lane] = u3;
    v[(n0+0)*64+lane] = v0; v[(n0+1)*64+lane] = v1;
    v[(n0+2)*64+lane] = v2; v[(n0+3)*64+lane] = v3;
  }
}

// ---------- fused CSR gather + MFMA post GEMM (v2) ----------
// Block = 4 waves, GN=32 nodes. Gather: lane c owns feature pair (2c,2c+1),
// lane-halves split edges, shfl_xor(32) combine, direct bf16 hi/lo pack to LDS.
// MFMA: waves 0,1 own ntile 0,1; W-fragments re-read from global (L2) per group.
__global__ __launch_bounds__(256, 4) void k_agg(
    const float* __restrict__ xin, const float* __restrict__ u,
    const float* __restrict__ v,
    const int* __restrict__ rowptr, const int* __restrict__ srcs,
    const uint4* __restrict__ Wfrag, const float* __restrict__ bc,
    float* __restrict__ hout){
  __shared__ __align__(16) unsigned Zh[GN*132];     // packed bf16-hi pairs
  __shared__ __align__(16) unsigned Zl[GN*132];     // packed bf16-lo pairs
  const int tid = threadIdx.x;
  const int lane = tid & 63;
  const int w = tid >> 6;
  const int c = lane & 31;        // feature-pair index
  const int h = lane >> 5;        // lane half
  const float bias = (w < 2) ? bc[w*32 + c] : 0.f;
  const uint4* WH = Wfrag + w*1024;        // valid for w<2
  const uint4* WL = Wfrag + (2+w)*1024;

  for (int g = blockIdx.x; g < NN/GN; g += gridDim.x){
    const int n0 = g*GN;
    __syncthreads();                 // previous group's MFMA reads done
    // ---- gather: wave w -> rows w*8 .. w*8+7
    for (int nn = 0; nn < 8; nn++){
      const int node = n0 + w*8 + nn;
      const int r0 = rowptr[node], r1 = rowptr[node+1];
      const float2 up = *(const float2*)&u[node*64 + 2*c];
      const float2 xv = *(const float2*)&xin[node*64 + 2*c];
      float Sx = 0.f, Sy = 0.f;
      float Mx = -3.402823466e+38f, My = Mx;
      int j = r0 + h;                // halves take alternating edges
      for (; j + 6 < r1; j += 8){    // 8 edges per wave-iteration
        int s0 = srcs[j], s1 = srcs[j+2], s2 = srcs[j+4], s3 = srcs[j+6];
        float2 a0 = *(const float2*)&v[s0*64 + 2*c];
        float2 a1 = *(const float2*)&v[s1*64 + 2*c];
        float2 a2 = *(const float2*)&v[s2*64 + 2*c];
        float2 a3 = *(const float2*)&v[s3*64 + 2*c];
        Sx += (a0.x + a1.x) + (a2.x + a3.x);
        Sy += (a0.y + a1.y) + (a2.y + a3.y);
        Mx = fmaxf(Mx, fmaxf(fmaxf(a0.x, a1.x), fmaxf(a2.x, a3.x)));
        My = fmaxf(My, fmaxf(fmaxf(a0.y, a1.y), fmaxf(a2.y, a3.y)));
      }
      for (; j < r1; j += 2){
        float2 a = *(const float2*)&v[srcs[j]*64 + 2*c];
        Sx += a.x; Sy += a.y;
        Mx = fmaxf(Mx, a.x); My = fmaxf(My, a.y);
      }
      // cross-half combine
      Sx += __shfl_xor(Sx, 32, 64);
      Sy += __shfl_xor(Sy, 32, 64);
      Mx = fmaxf(Mx, __shfl_xor(Mx, 32, 64));
      My = fmaxf(My, __shfl_xor(My, 32, 64));

      const int d = r1 - r0;
      float2 z1, z2, z3;
      if (d > 0){
        float fd = (float)d;
        z1.x = up.x + Sx/fd;  z1.y = up.y + Sy/fd;
        z2.x = up.x + Mx;     z2.y = up.y + My;
        z3.x = fmaf(fd, up.x, Sx); z3.y = fmaf(fd, up.y, Sy);
      } else {
        z1.x=z1.y=z2.x=z2.y=z3.x=z3.y=0.f;   // PyG empty-segment semantics
      }
      // direct pack: half 0 writes hi plane, half 1 writes lo plane
      const int row = w*8 + nn;
      float2 q[4] = {xv, z1, z2, z3};
      #pragma unroll
      for (int qq = 0; qq < 4; qq++){
        unsigned u0 = __float_as_uint(q[qq].x), u1 = __float_as_uint(q[qq].y);
        if (h == 0){
          Zh[row*132 + qq*32 + c] = pk_hi(u1, u0);
        } else {
          float r0f = q[qq].x - __uint_as_float(u0 & 0xFFFF0000u);
          float r1f = q[qq].y - __uint_as_float(u1 & 0xFFFF0000u);
          Zl[row*132 + qq*32 + c] = pk_hi(__float_as_uint(r1f), __float_as_uint(r0f));
        }
      }
    }
    __syncthreads();
    // ---- MFMA: waves 0,1; 48 MFMAs each (Ah*Wh + Al*Wh + Ah*Wl)
    if (w < 2){
      f32x16 acc = {};
      const int arow = c*132 + h*4;
      #pragma unroll 4
      for (int s = 0; s < 16; s++){
        uint4 ah = *(const uint4*)&Zh[arow + s*8];
        uint4 al = *(const uint4*)&Zl[arow + s*8];
        uint4 bh = WH[s*64 + lane];
        uint4 bl = WL[s*64 + lane];
        acc = mfma_b(ah, bh, acc);
        acc = mfma_b(al, bh, acc);
        acc = mfma_b(ah, bl, acc);
      }
      #pragma unroll
      for (int r = 0; r < 16; r++){
        int row = (r & 3) + 8*(r >> 2) + 4*h;   // verified C/D layout
        float val = fmaxf(acc[r] + bias, 0.f);
        hout[(size_t)(n0 + row)*64 + w*32 + c] = val;
      }
    }
  }
}

// ---------- classifier: 8 nodes per wave (4 pairs), h rows in registers ----------
__global__ __launch_bounds__(512, 2) void k_cls(
    const float* __restrict__ h, const float* __restrict__ Wf,
    const float* __restrict__ bfv, float* __restrict__ out){
  __shared__ float WT[64*NCLS];     // WT[k*32 + c] = Wf[c*64+k]
  __shared__ float bS[NCLS];
  const int tid = threadIdx.x;
  for (int i = tid; i < 64*NCLS; i += 512){
    int k = i >> 5, c = i & 31;
    WT[k*NCLS + c] = Wf[c*64 + k];
  }
  if (tid < NCLS) bS[tid] = bfv[tid];
  __syncthreads();

  const int lane = tid & 63;
  const int wid = blockIdx.x*8 + (tid >> 6);
  const int nwaves = gridDim.x*8;
  const int c = lane & 31;
  const bool hi = lane >= 32;
  const float bias = bS[c];
  for (int g = wid; g < NN/8; g += nwaves){
    const int n0 = g*8;
    float h0 = h[(n0+0)*64+lane], h1 = h[(n0+1)*64+lane];
    float h2 = h[(n0+2)*64+lane], h3 = h[(n0+3)*64+lane];
    float h4 = h[(n0+4)*64+lane], h5 = h[(n0+5)*64+lane];
    float h6 = h[(n0+6)*64+lane], h7 = h[(n0+7)*64+lane];
    float acc0 = bias, acc1 = bias, acc2 = bias, acc3 = bias;
    #pragma unroll 4
    for (int k = 0; k < 64; k++){
      float wv = WT[k*NCLS + c];
      float e0 = rlf(h0,k), e1 = rlf(h1,k), e2 = rlf(h2,k), e3 = rlf(h3,k);
      float e4 = rlf(h4,k), e5 = rlf(h5,k), e6 = rlf(h6,k), e7 = rlf(h7,k);
      acc0 = fmaf(hi ? e1 : e0, wv, acc0);
      acc1 = fmaf(hi ? e3 : e2, wv, acc1);
      acc2 = fmaf(hi ? e5 : e4, wv, acc2);
      acc3 = fmaf(hi ? e7 : e6, wv, acc3);
    }
    out[n0*NCLS +   0 + lane] = acc0;
    out[n0*NCLS +  64 + lane] = acc1;
    out[n0*NCLS + 128 + lane] = acc2;
    out[n0*NCLS + 192 + lane] = acc3;
  }
}

extern "C" void kernel_launch(void* const* d_in, const int* in_sizes, int n_in,
                              void* d_out, int out_size, void* d_ws, size_t ws_size,
                              hipStream_t stream){
  const float* x      = (const float*)d_in[0];
  const int*   ei     = (const int*)  d_in[1];
  const int*   src    = ei;
  const int*   dst    = ei + NE;
  const float* W1_pre = (const float*)d_in[2];
  const float* b1_pre = (const float*)d_in[3];
  const float* W1_post= (const float*)d_in[4];
  const float* b1_post= (const float*)d_in[5];
  const float* W1_lin = (const float*)d_in[6];
  const float* b1_lin = (const float*)d_in[7];
  const float* W2_pre = (const float*)d_in[8];
  const float* b2_pre = (const float*)d_in[9];
  const float* W2_post= (const float*)d_in[10];
  const float* b2_post= (const float*)d_in[11];
  const float* W2_lin = (const float*)d_in[12];
  const float* b2_lin = (const float*)d_in[13];
  const float* Wf     = (const float*)d_in[14];
  const float* bf     = (const float*)d_in[15];
  float* out = (float*)d_out;

  size_t off = 0;
  char* ws = (char*)d_ws;
  auto alloc = [&](size_t bytes){ void* p = ws + off; off += (bytes + 255) & ~(size_t)255; return p; };
  int*   deg    = (int*)  alloc(NN*4);
  int*   rowptr = (int*)  alloc((NN+1)*4);
  int*   cursor = (int*)  alloc(NN*4);
  int*   inc    = (int*)  alloc(NB*256*4);
  int*   part   = (int*)  alloc(512*4);
  int*   srcs   = (int*)  alloc((size_t)NE*4);
  float* u      = (float*)alloc((size_t)NN*64*4);
  float* v      = (float*)alloc((size_t)NN*64*4);
  float* h1     = (float*)alloc((size_t)NN*64*4);
  float* Wc1T   = (float*)alloc(256*64*4);
  float* bc1    = (float*)alloc(64*4);
  float* Wc2T   = (float*)alloc(256*64*4);
  float* bc2    = (float*)alloc(64*4);
  uint4* Wfrag1 = (uint4*)alloc(4096*16);
  uint4* Wfrag2 = (uint4*)alloc(4096*16);
  float* h2;
  if (off + (size_t)NN*64*4 <= ws_size) h2 = (float*)alloc((size_t)NN*64*4);
  else h2 = h1;   // safe alias: layer-2 k_agg reads xin only at its own rows before writing them

  // weight folding + fragment emission
  k_prep<<<64, 256, 0, stream>>>(W1_lin, b1_lin, W1_post, b1_post, Wc1T, bc1);
  k_prep<<<64, 256, 0, stream>>>(W2_lin, b2_lin, W2_post, b2_post, Wc2T, bc2);
  k_wfrag<<<16, 256, 0, stream>>>(Wc1T, Wfrag1);
  k_wfrag<<<16, 256, 0, stream>>>(Wc2T, Wfrag2);

  // CSR build (shared by both layers)
  k_zero_i<<<NB, 256, 0, stream>>>(deg, NN);
  k_deg<<<(NE+255)/256, 256, 0, stream>>>(dst, deg);
  k_scan1<<<NB, 256, 0, stream>>>(deg, inc, part);
  k_scan2<<<1, 512, 0, stream>>>(part);
  k_scan3<<<NB, 256, 0, stream>>>(inc, part, deg, rowptr, cursor);
  k_scatter<<<(NE+255)/256, 256, 0, stream>>>(src, dst, cursor, srcs);

  // layer 1
  k_uv <<<1024, 512, 0, stream>>>(x, W1_pre, b1_pre, u, v);
  k_agg<<<2048, 256, 0, stream>>>(x, u, v, rowptr, srcs, Wfrag1, bc1, h1);

  // layer 2 (h2 may alias h1 — in-place safe)
  k_uv <<<1024, 512, 0, stream>>>(h1, W2_pre, b2_pre, u, v);
  k_agg<<<2048, 256, 0, stream>>>(h1, u, v, rowptr, srcs, Wfrag2, bc2, h2);

  // classifier
  k_cls<<<512, 512, 0, stream>>>(h2, Wf, bf, out);
}

// Round 8
// 331.607 us; speedup vs baseline: 10.6047x; 1.5190x over previous
//
#include <hip/hip_runtime.h>

#define NN 100000
#define NE 1000000
#define NCLS 32
#define NB 391            // ceil(NN/256)
#define GN 32             // nodes per k_agg group
#define NGROUPS (NN/GN)   // 3125
#define UVG ((NN+63)/64)  // 1563 uv groups of 64 nodes

typedef __bf16 bf16x8 __attribute__((ext_vector_type(8)));
typedef float f32x16 __attribute__((ext_vector_type(16)));

// pack hi16 of two f32 into one u32: {hi16(f1) : hi16(f0)}  (f0 -> low half)
__device__ __forceinline__ unsigned pk_hi(unsigned u1, unsigned u0){
  return __builtin_amdgcn_perm(u1, u0, 0x07060302u);
}
__device__ __forceinline__ unsigned pk_lo(float f0, float f1, unsigned u0, unsigned u1){
  float r0 = f0 - __uint_as_float(u0 & 0xFFFF0000u);
  float r1 = f1 - __uint_as_float(u1 & 0xFFFF0000u);
  return pk_hi(__float_as_uint(r1), __float_as_uint(r0));
}
__device__ __forceinline__ f32x16 mfma_b(uint4 a, uint4 b, f32x16 c){
  bf16x8 av, bv;
  __builtin_memcpy(&av, &a, 16);
  __builtin_memcpy(&bv, &b, 16);
  return __builtin_amdgcn_mfma_f32_32x32x16_bf16(av, bv, c, 0, 0, 0);
}
__device__ __forceinline__ int crow(int r, int half){ return (r&3) + 8*(r>>2) + 4*half; }

// ---------- one-shot setup: all weight fragments + bc + zero deg ----------
__global__ void k_setup(const float* __restrict__ W1_lin, const float* __restrict__ b1_lin,
                        const float* __restrict__ W1_post, const float* __restrict__ b1_post,
                        const float* __restrict__ W2_lin, const float* __restrict__ b2_lin,
                        const float* __restrict__ W2_post, const float* __restrict__ b2_post,
                        const float* __restrict__ W1_pre, const float* __restrict__ W2_pre,
                        const float* __restrict__ Wf,
                        uint4* __restrict__ Wcf, uint4* __restrict__ Wpf,
                        uint4* __restrict__ Wff, float* __restrict__ bc,
                        int* __restrict__ deg){
  const int blk = blockIdx.x, tid = threadIdx.x;
  if (blk < 16){
    int i = blk*256 + tid;                    // [0, 4096)
    int layer = i >> 11;
    int t = (i >> 10) & 1, step = (i >> 6) & 15, lane = i & 63;
    const float* Wlin  = layer ? W2_lin  : W1_lin;
    const float* Wpost = layer ? W2_post : W1_post;
    int col = t*32 + (lane & 31);
    int k0 = step*16 + ((lane >> 5) << 3);
    unsigned hi[4], lo[4];
    for (int p = 0; p < 4; p++){
      float f0 = 0.f, f1 = 0.f;
      for (int j = 0; j < 64; j++){
        float wl = Wlin[col*64 + j];
        f0 += wl * Wpost[j*256 + k0 + 2*p];
        f1 += wl * Wpost[j*256 + k0 + 2*p + 1];
      }
      unsigned u0 = __float_as_uint(f0), u1 = __float_as_uint(f1);
      hi[p] = pk_hi(u1, u0);
      lo[p] = pk_lo(f0, f1, u0, u1);
    }
    uint4* base = Wcf + layer*4096;
    base[t*1024     + step*64 + lane] = make_uint4(hi[0],hi[1],hi[2],hi[3]);
    base[(2+t)*1024 + step*64 + lane] = make_uint4(lo[0],lo[1],lo[2],lo[3]);
  } else if (blk < 24){
    int i = (blk-16)*256 + tid;               // [0, 2048)
    int layer = i >> 10;
    int t = (i >> 8) & 3, st = (i >> 6) & 3, lane = i & 63;
    const float* Wpre = layer ? W2_pre : W1_pre;
    int col = t*32 + (lane & 31);             // 0..127 (u | v)
    int o = col & 63, koff = (col >> 6) * 64;
    int k0 = st*16 + ((lane >> 5) << 3);
    unsigned hi[4], lo[4];
    for (int p = 0; p < 4; p++){
      float f0 = Wpre[o*128 + koff + k0 + 2*p];
      float f1 = Wpre[o*128 + koff + k0 + 2*p + 1];
      unsigned u0 = __float_as_uint(f0), u1 = __float_as_uint(f1);
      hi[p] = pk_hi(u1, u0);
      lo[p] = pk_lo(f0, f1, u0, u1);
    }
    uint4* base = Wpf + layer*2048 + t*512;
    base[st*64 + lane]       = make_uint4(hi[0],hi[1],hi[2],hi[3]);
    base[256 + st*64 + lane] = make_uint4(lo[0],lo[1],lo[2],lo[3]);
  } else if (blk == 24){
    int st = tid >> 6, lane = tid & 63;       // 256 threads exactly
    int cls = lane & 31;
    int k0 = st*16 + ((lane >> 5) << 3);
    unsigned hi[4], lo[4];
    for (int p = 0; p < 4; p++){
      float f0 = Wf[cls*64 + k0 + 2*p];
      float f1 = Wf[cls*64 + k0 + 2*p + 1];
      unsigned u0 = __float_as_uint(f0), u1 = __float_as_uint(f1);
      hi[p] = pk_hi(u1, u0);
      lo[p] = pk_lo(f0, f1, u0, u1);
    }
    Wff[st*64 + lane]       = make_uint4(hi[0],hi[1],hi[2],hi[3]);
    Wff[256 + st*64 + lane] = make_uint4(lo[0],lo[1],lo[2],lo[3]);
  } else if (blk == 25){
    if (tid < 128){
      int layer = tid >> 6, o = tid & 63;
      const float* Wlin  = layer ? W2_lin  : W1_lin;
      const float* blin  = layer ? b2_lin  : b1_lin;
      const float* bpost = layer ? b2_post : b1_post;
      float s = blin[o];
      for (int j = 0; j < 64; j++) s += Wlin[o*64+j] * bpost[j];
      bc[tid] = s;
    }
  } else {
    int i = (blk-26)*256 + tid;
    if (i < NN) deg[i] = 0;
  }
}

// ---------- CSR build ----------
__global__ void k_deg(const int* __restrict__ dst, int* __restrict__ deg){
  int e = blockIdx.x*256 + threadIdx.x;
  if (e < NE) atomicAdd(&deg[dst[e]], 1);
}

__global__ void k_scan1(const int* __restrict__ deg, int* __restrict__ inc,
                        int* __restrict__ part){
  __shared__ int s[256];
  int tid = threadIdx.x;
  int i = blockIdx.x*256 + tid;
  s[tid] = (i < NN) ? deg[i] : 0;
  __syncthreads();
  for (int off = 1; off < 256; off <<= 1){
    int t = (tid >= off) ? s[tid-off] : 0;
    __syncthreads();
    s[tid] += t;
    __syncthreads();
  }
  inc[i] = s[tid];
  if (tid == 255) part[blockIdx.x] = s[255];
}

// each block re-scans all partials in LDS, then emits rowptr + cursor
__global__ void k_scan23(const int* __restrict__ inc, const int* __restrict__ part,
                         const int* __restrict__ deg,
                         int* __restrict__ rowptr, int* __restrict__ cursor){
  __shared__ int s[512];
  int tid = threadIdx.x;
  s[tid] = (tid < NB) ? part[tid] : 0;
  __syncthreads();
  for (int off = 1; off < 512; off <<= 1){
    int t = (tid >= off) ? s[tid-off] : 0;
    __syncthreads();
    s[tid] += t;
    __syncthreads();
  }
  int b = blockIdx.x;
  int base = b ? s[b-1] : 0;
  if (tid < 256){
    int i = b*256 + tid;
    if (i < NN){
      int inclusive = inc[i] + base;
      rowptr[i+1] = inclusive;
      cursor[i] = inclusive - deg[i];
    }
  }
  if (b == 0 && tid == 0) rowptr[0] = 0;
}

__global__ void k_scatter(const int* __restrict__ src, const int* __restrict__ dst,
                          int* __restrict__ cursor, int* __restrict__ srcs){
  int e = blockIdx.x*256 + threadIdx.x;
  if (e < NE){
    int d = dst[e];
    int p = atomicAdd(&cursor[d], 1);
    srcs[p] = src[e];
  }
}

// ---------- per-node pre-transform via MFMA: [u|v] = x @ Wpre^T (+bpre on u) ----------
__global__ __launch_bounds__(512, 4) void k_uv(
    const float* __restrict__ xin, const uint4* __restrict__ Wpf,
    const float* __restrict__ bpre, float* __restrict__ u, float* __restrict__ v){
  __shared__ __align__(16) unsigned XH[64*36];
  __shared__ __align__(16) unsigned XL[64*36];
  const int tid = threadIdx.x;
  const int lane = tid & 63;
  const int w = tid >> 6;
  const int t = w >> 1, rg = w & 1;
  const int cc = lane & 31, half = lane >> 5;
  const int col = t*32 + cc;
  uint4 wfr[2][4];
  {
    const uint4* p = Wpf + t*512;
    #pragma unroll
    for (int s = 0; s < 2; s++)
      #pragma unroll
      for (int st = 0; st < 4; st++) wfr[s][st] = p[s*256 + st*64 + lane];
  }
  const float bias = (t < 2) ? bpre[col] : 0.f;
  float* const dstp = (t < 2) ? u : v;
  const int dcol = col & 63;
  const int srow = tid >> 3, sq = tid & 7;

  for (int g = blockIdx.x; g < UVG; g += gridDim.x){
    const int n0 = g*64;
    __syncthreads();                 // previous group's A-frag reads done
    {
      const int node = n0 + srow;
      float4 a = {0,0,0,0}, b = {0,0,0,0};
      if (node < NN){
        a = *(const float4*)&xin[(size_t)node*64 + sq*8];
        b = *(const float4*)&xin[(size_t)node*64 + sq*8 + 4];
      }
      unsigned ax = __float_as_uint(a.x), ay = __float_as_uint(a.y);
      unsigned az = __float_as_uint(a.z), aw = __float_as_uint(a.w);
      unsigned bx = __float_as_uint(b.x), by = __float_as_uint(b.y);
      unsigned bz = __float_as_uint(b.z), bw = __float_as_uint(b.w);
      uint4 hi, lo;
      hi.x = pk_hi(ay, ax); lo.x = pk_lo(a.x, a.y, ax, ay);
      hi.y = pk_hi(aw, az); lo.y = pk_lo(a.z, a.w, az, aw);
      hi.z = pk_hi(by, bx); lo.z = pk_lo(b.x, b.y, bx, by);
      hi.w = pk_hi(bw, bz); lo.w = pk_lo(b.z, b.w, bz, bw);
      *(uint4*)&XH[srow*36 + sq*4] = hi;
      *(uint4*)&XL[srow*36 + sq*4] = lo;
    }
    __syncthreads();
    f32x16 acc = {};
    const int arow = (rg*32 + cc)*36 + half*4;
    #pragma unroll
    for (int st = 0; st < 4; st++){
      uint4 ah = *(const uint4*)&XH[arow + st*8];
      uint4 al = *(const uint4*)&XL[arow + st*8];
      acc = mfma_b(ah, wfr[0][st], acc);
      acc = mfma_b(al, wfr[0][st], acc);
      acc = mfma_b(ah, wfr[1][st], acc);
    }
    #pragma unroll
    for (int r = 0; r < 16; r++){
      int row = n0 + rg*32 + crow(r, half);
      if (row < NN) dstp[(size_t)row*64 + dcol] = acc[r] + bias;
    }
  }
}

// ---------- fused CSR gather + MFMA post GEMM (+ fused classifier if EPI==1) ----------
// 512 thr / 8 waves, GN=32; each wave gathers 4 nodes; waves 0,1 do post-MFMA.
// EPI==1: barrier BEFORE HF write-back into Zh (both MFMA waves read all Zh rows).
template<int EPI>
__global__ __launch_bounds__(512, 8) void k_agg(
    const float* __restrict__ xin, const float* __restrict__ u,
    const float* __restrict__ v,
    const int* __restrict__ rowptr, const int* __restrict__ srcs,
    const uint4* __restrict__ Wcf, const float* __restrict__ bcv,
    const uint4* __restrict__ Wff, const float* __restrict__ bfv,
    float* __restrict__ hout, float* __restrict__ outp){
  __shared__ __align__(16) unsigned Zh[GN*132];
  __shared__ __align__(16) unsigned Zl[GN*132];
  const int tid = threadIdx.x;
  const int lane = tid & 63;
  const int w = tid >> 6;
  const int c = lane & 31;
  const int h = lane >> 5;
  const float bias = (w < 2) ? bcv[w*32 + c] : 0.f;
  const uint4* WH = Wcf + w*1024;
  const uint4* WL = Wcf + (2+w)*1024;

  for (int g = blockIdx.x; g < NGROUPS; g += gridDim.x){
    const int n0 = g*GN;
    __syncthreads();                 // previous group's LDS reads done
    // ---- gather: wave w -> rows w*4 .. w*4+3
    for (int nn = 0; nn < 4; nn++){
      const int node = n0 + w*4 + nn;
      const int r0 = rowptr[node], r1 = rowptr[node+1];
      const float2 up = *(const float2*)&u[(size_t)node*64 + 2*c];
      const float2 xv = *(const float2*)&xin[(size_t)node*64 + 2*c];
      float Sx = 0.f, Sy = 0.f;
      float Mx = -3.402823466e+38f, My = Mx;
      int j = r0 + h;                // halves take alternating edges
      for (; j + 6 < r1; j += 8){
        int s0 = srcs[j], s1 = srcs[j+2], s2 = srcs[j+4], s3 = srcs[j+6];
        float2 a0 = *(const float2*)&v[(size_t)s0*64 + 2*c];
        float2 a1 = *(const float2*)&v[(size_t)s1*64 + 2*c];
        float2 a2 = *(const float2*)&v[(size_t)s2*64 + 2*c];
        float2 a3 = *(const float2*)&v[(size_t)s3*64 + 2*c];
        Sx += (a0.x + a1.x) + (a2.x + a3.x);
        Sy += (a0.y + a1.y) + (a2.y + a3.y);
        Mx = fmaxf(Mx, fmaxf(fmaxf(a0.x, a1.x), fmaxf(a2.x, a3.x)));
        My = fmaxf(My, fmaxf(fmaxf(a0.y, a1.y), fmaxf(a2.y, a3.y)));
      }
      for (; j < r1; j += 2){
        float2 a = *(const float2*)&v[(size_t)srcs[j]*64 + 2*c];
        Sx += a.x; Sy += a.y;
        Mx = fmaxf(Mx, a.x); My = fmaxf(My, a.y);
      }
      Sx += __shfl_xor(Sx, 32, 64);
      Sy += __shfl_xor(Sy, 32, 64);
      Mx = fmaxf(Mx, __shfl_xor(Mx, 32, 64));
      My = fmaxf(My, __shfl_xor(My, 32, 64));

      const int d = r1 - r0;
      float2 z1, z2, z3;
      if (d > 0){
        float fd = (float)d;
        z1.x = up.x + Sx/fd;  z1.y = up.y + Sy/fd;
        z2.x = up.x + Mx;     z2.y = up.y + My;
        z3.x = fmaf(fd, up.x, Sx); z3.y = fmaf(fd, up.y, Sy);
      } else {
        z1.x=z1.y=z2.x=z2.y=z3.x=z3.y=0.f;   // PyG empty-segment semantics
      }
      const int row = w*4 + nn;
      float2 q[4] = {xv, z1, z2, z3};
      #pragma unroll
      for (int qq = 0; qq < 4; qq++){
        unsigned u0 = __float_as_uint(q[qq].x), u1 = __float_as_uint(q[qq].y);
        if (h == 0) Zh[row*132 + qq*32 + c] = pk_hi(u1, u0);
        else        Zl[row*132 + qq*32 + c] = pk_lo(q[qq].x, q[qq].y, u0, u1);
      }
    }
    __syncthreads();
    // ---- post-GEMM MFMA: waves 0,1
    f32x16 acc = {};
    if (w < 2){
      const int arow = c*132 + h*4;
      #pragma unroll 4
      for (int s = 0; s < 16; s++){
        uint4 ah = *(const uint4*)&Zh[arow + s*8];
        uint4 al = *(const uint4*)&Zl[arow + s*8];
        uint4 bh = WH[s*64 + lane];
        uint4 bl = WL[s*64 + lane];
        acc = mfma_b(ah, bh, acc);
        acc = mfma_b(al, bh, acc);
        acc = mfma_b(ah, bl, acc);
      }
      if (EPI == 0){
        #pragma unroll
        for (int r = 0; r < 16; r++){
          float val = fmaxf(acc[r] + bias, 0.f);
          hout[(size_t)(n0 + crow(r,h))*64 + w*32 + c] = val;
        }
      }
    }
    if (EPI == 1){
      __syncthreads();               // BOTH MFMA waves done READING Zh/Zl
      if (w < 2){
        float* HF = (float*)Zh;      // now safe to reuse Zh
        #pragma unroll
        for (int r = 0; r < 16; r++){
          float val = fmaxf(acc[r] + bias, 0.f);
          HF[crow(r,h)*64 + w*32 + c] = val;
        }
      }
      __syncthreads();               // HF complete
      {
        const float* HF = (const float*)Zh;
        unsigned* HH = Zl;
        unsigned* HL = Zl + 1152;
        const int row = tid >> 4, p4 = tid & 15;
        float4 f = *(const float4*)&HF[row*64 + p4*4];
        unsigned f0 = __float_as_uint(f.x), f1 = __float_as_uint(f.y);
        unsigned f2 = __float_as_uint(f.z), f3 = __float_as_uint(f.w);
        HH[row*36 + p4*2]   = pk_hi(f1, f0);
        HH[row*36 + p4*2+1] = pk_hi(f3, f2);
        HL[row*36 + p4*2]   = pk_lo(f.x, f.y, f0, f1);
        HL[row*36 + p4*2+1] = pk_lo(f.z, f.w, f2, f3);
      }
      __syncthreads();               // HH/HL complete
      if (w == 0){
        f32x16 ac2 = {};
        const unsigned* HH = Zl;
        const unsigned* HL = Zl + 1152;
        const int arow = c*36 + h*4;
        #pragma unroll
        for (int st = 0; st < 4; st++){
          uint4 ah = *(const uint4*)&HH[arow + st*8];
          uint4 al = *(const uint4*)&HL[arow + st*8];
          uint4 bh = Wff[st*64 + lane];
          uint4 bl = Wff[256 + st*64 + lane];
          ac2 = mfma_b(ah, bh, ac2);
          ac2 = mfma_b(al, bh, ac2);
          ac2 = mfma_b(ah, bl, ac2);
        }
        const float bcls = bfv[c];
        #pragma unroll
        for (int r = 0; r < 16; r++)
          outp[(size_t)(n0 + crow(r,h))*NCLS + c] = ac2[r] + bcls;
      }
    }
  }
}

extern "C" void kernel_launch(void* const* d_in, const int* in_sizes, int n_in,
                              void* d_out, int out_size, void* d_ws, size_t ws_size,
                              hipStream_t stream){
  const float* x      = (const float*)d_in[0];
  const int*   ei     = (const int*)  d_in[1];
  const int*   src    = ei;
  const int*   dst    = ei + NE;
  const float* W1_pre = (const float*)d_in[2];
  const float* b1_pre = (const float*)d_in[3];
  const float* W1_post= (const float*)d_in[4];
  const float* b1_post= (const float*)d_in[5];
  const float* W1_lin = (const float*)d_in[6];
  const float* b1_lin = (const float*)d_in[7];
  const float* W2_pre = (const float*)d_in[8];
  const float* b2_pre = (const float*)d_in[9];
  const float* W2_post= (const float*)d_in[10];
  const float* b2_post= (const float*)d_in[11];
  const float* W2_lin = (const float*)d_in[12];
  const float* b2_lin = (const float*)d_in[13];
  const float* Wf     = (const float*)d_in[14];
  const float* bf     = (const float*)d_in[15];
  float* out = (float*)d_out;

  size_t off = 0;
  char* ws = (char*)d_ws;
  auto alloc = [&](size_t bytes){ void* p = ws + off; off += (bytes + 255) & ~(size_t)255; return p; };
  int*   deg    = (int*)  alloc(NN*4);
  int*   rowptr = (int*)  alloc((NN+1)*4);
  int*   cursor = (int*)  alloc(NN*4);
  int*   inc    = (int*)  alloc(NB*256*4);
  int*   part   = (int*)  alloc(512*4);
  int*   srcs   = (int*)  alloc((size_t)NE*4);
  float* u      = (float*)alloc((size_t)NN*64*4);
  float* v      = (float*)alloc((size_t)NN*64*4);
  float* h1     = (float*)alloc((size_t)NN*64*4);
  uint4* Wcf    = (uint4*)alloc(2*4096*16);
  uint4* Wpf    = (uint4*)alloc(4096*16);
  uint4* Wff    = (uint4*)alloc(512*16);
  float* bc     = (float*)alloc(128*4);

  // 1. all weight fragments + bc + zero deg, in one kernel
  k_setup<<<417, 256, 0, stream>>>(W1_lin, b1_lin, W1_post, b1_post,
                                   W2_lin, b2_lin, W2_post, b2_post,
                                   W1_pre, W2_pre, Wf, Wcf, Wpf, Wff, bc, deg);
  // 2-5. CSR build
  k_deg    <<<(NE+255)/256, 256, 0, stream>>>(dst, deg);
  k_scan1  <<<NB, 256, 0, stream>>>(deg, inc, part);
  k_scan23 <<<NB, 512, 0, stream>>>(inc, part, deg, rowptr, cursor);
  k_scatter<<<(NE+255)/256, 256, 0, stream>>>(src, dst, cursor, srcs);

  // layer 1
  k_uv    <<<1024, 512, 0, stream>>>(x, Wpf, b1_pre, u, v);
  k_agg<0><<<1024, 512, 0, stream>>>(x, u, v, rowptr, srcs, Wcf, bc,
                                     nullptr, nullptr, h1, nullptr);

  // layer 2 (+ fused classifier; h2 never hits HBM)
  k_uv    <<<1024, 512, 0, stream>>>(h1, Wpf + 2048, b2_pre, u, v);
  k_agg<1><<<1024, 512, 0, stream>>>(h1, u, v, rowptr, srcs, Wcf + 4096, bc + 64,
                                     Wff, bf, nullptr, out);
}

// Round 9
// 310.020 us; speedup vs baseline: 11.3431x; 1.0696x over previous
//
#include <hip/hip_runtime.h>

#define NN 100000
#define NE 1000000
#define NCLS 32
#define NB 391            // ceil(NN/256)
#define GN 32             // nodes per k_agg group
#define NGROUPS (NN/GN)   // 3125
#define UVG ((NN+63)/64)  // 1563 uv groups of 64 nodes

typedef __bf16 bf16x8 __attribute__((ext_vector_type(8)));
typedef float f32x16 __attribute__((ext_vector_type(16)));

// pack hi16 of two f32 into one u32: {hi16(f1) : hi16(f0)}  (f0 -> low half)
__device__ __forceinline__ unsigned pk_hi(unsigned u1, unsigned u0){
  return __builtin_amdgcn_perm(u1, u0, 0x07060302u);
}
__device__ __forceinline__ unsigned pk_lo(float f0, float f1, unsigned u0, unsigned u1){
  float r0 = f0 - __uint_as_float(u0 & 0xFFFF0000u);
  float r1 = f1 - __uint_as_float(u1 & 0xFFFF0000u);
  return pk_hi(__float_as_uint(r1), __float_as_uint(r0));
}
__device__ __forceinline__ f32x16 mfma_b(uint4 a, uint4 b, f32x16 c){
  bf16x8 av, bv;
  __builtin_memcpy(&av, &a, 16);
  __builtin_memcpy(&bv, &b, 16);
  return __builtin_amdgcn_mfma_f32_32x32x16_bf16(av, bv, c, 0, 0, 0);
}
__device__ __forceinline__ int crow(int r, int half){ return (r&3) + 8*(r>>2) + 4*half; }

// ---------- one-shot setup: all weight fragments + bc + zero deg ----------
__global__ void k_setup(const float* __restrict__ W1_lin, const float* __restrict__ b1_lin,
                        const float* __restrict__ W1_post, const float* __restrict__ b1_post,
                        const float* __restrict__ W2_lin, const float* __restrict__ b2_lin,
                        const float* __restrict__ W2_post, const float* __restrict__ b2_post,
                        const float* __restrict__ W1_pre, const float* __restrict__ W2_pre,
                        const float* __restrict__ Wf,
                        uint4* __restrict__ Wcf, uint4* __restrict__ Wpf,
                        uint4* __restrict__ Wff, float* __restrict__ bc,
                        int* __restrict__ deg){
  const int blk = blockIdx.x, tid = threadIdx.x;
  if (blk < 16){
    int i = blk*256 + tid;                    // [0, 4096)
    int layer = i >> 11;
    int t = (i >> 10) & 1, step = (i >> 6) & 15, lane = i & 63;
    const float* Wlin  = layer ? W2_lin  : W1_lin;
    const float* Wpost = layer ? W2_post : W1_post;
    int col = t*32 + (lane & 31);
    int k0 = step*16 + ((lane >> 5) << 3);
    unsigned hi[4], lo[4];
    for (int p = 0; p < 4; p++){
      float f0 = 0.f, f1 = 0.f;
      for (int j = 0; j < 64; j++){
        float wl = Wlin[col*64 + j];
        f0 += wl * Wpost[j*256 + k0 + 2*p];
        f1 += wl * Wpost[j*256 + k0 + 2*p + 1];
      }
      unsigned u0 = __float_as_uint(f0), u1 = __float_as_uint(f1);
      hi[p] = pk_hi(u1, u0);
      lo[p] = pk_lo(f0, f1, u0, u1);
    }
    uint4* base = Wcf + layer*4096;
    base[t*1024     + step*64 + lane] = make_uint4(hi[0],hi[1],hi[2],hi[3]);
    base[(2+t)*1024 + step*64 + lane] = make_uint4(lo[0],lo[1],lo[2],lo[3]);
  } else if (blk < 24){
    int i = (blk-16)*256 + tid;               // [0, 2048)
    int layer = i >> 10;
    int t = (i >> 8) & 3, st = (i >> 6) & 3, lane = i & 63;
    const float* Wpre = layer ? W2_pre : W1_pre;
    int col = t*32 + (lane & 31);             // 0..127 (u | v)
    int o = col & 63, koff = (col >> 6) * 64;
    int k0 = st*16 + ((lane >> 5) << 3);
    unsigned hi[4], lo[4];
    for (int p = 0; p < 4; p++){
      float f0 = Wpre[o*128 + koff + k0 + 2*p];
      float f1 = Wpre[o*128 + koff + k0 + 2*p + 1];
      unsigned u0 = __float_as_uint(f0), u1 = __float_as_uint(f1);
      hi[p] = pk_hi(u1, u0);
      lo[p] = pk_lo(f0, f1, u0, u1);
    }
    uint4* base = Wpf + layer*2048 + t*512;
    base[st*64 + lane]       = make_uint4(hi[0],hi[1],hi[2],hi[3]);
    base[256 + st*64 + lane] = make_uint4(lo[0],lo[1],lo[2],lo[3]);
  } else if (blk == 24){
    int st = tid >> 6, lane = tid & 63;       // 256 threads exactly
    int cls = lane & 31;
    int k0 = st*16 + ((lane >> 5) << 3);
    unsigned hi[4], lo[4];
    for (int p = 0; p < 4; p++){
      float f0 = Wf[cls*64 + k0 + 2*p];
      float f1 = Wf[cls*64 + k0 + 2*p + 1];
      unsigned u0 = __float_as_uint(f0), u1 = __float_as_uint(f1);
      hi[p] = pk_hi(u1, u0);
      lo[p] = pk_lo(f0, f1, u0, u1);
    }
    Wff[st*64 + lane]       = make_uint4(hi[0],hi[1],hi[2],hi[3]);
    Wff[256 + st*64 + lane] = make_uint4(lo[0],lo[1],lo[2],lo[3]);
  } else if (blk == 25){
    if (tid < 128){
      int layer = tid >> 6, o = tid & 63;
      const float* Wlin  = layer ? W2_lin  : W1_lin;
      const float* blin  = layer ? b2_lin  : b1_lin;
      const float* bpost = layer ? b2_post : b1_post;
      float s = blin[o];
      for (int j = 0; j < 64; j++) s += Wlin[o*64+j] * bpost[j];
      bc[tid] = s;
    }
  } else {
    int i = (blk-26)*256 + tid;
    if (i < NN) deg[i] = 0;
  }
}

// ---------- CSR build ----------
__global__ void k_deg(const int* __restrict__ dst, int* __restrict__ deg){
  int e = blockIdx.x*256 + threadIdx.x;
  if (e < NE) atomicAdd(&deg[dst[e]], 1);
}

__global__ void k_scan1(const int* __restrict__ deg, int* __restrict__ inc,
                        int* __restrict__ part){
  __shared__ int s[256];
  int tid = threadIdx.x;
  int i = blockIdx.x*256 + tid;
  s[tid] = (i < NN) ? deg[i] : 0;
  __syncthreads();
  for (int off = 1; off < 256; off <<= 1){
    int t = (tid >= off) ? s[tid-off] : 0;
    __syncthreads();
    s[tid] += t;
    __syncthreads();
  }
  inc[i] = s[tid];
  if (tid == 255) part[blockIdx.x] = s[255];
}

// each block re-scans all partials in LDS, then emits rowptr + cursor
__global__ void k_scan23(const int* __restrict__ inc, const int* __restrict__ part,
                         const int* __restrict__ deg,
                         int* __restrict__ rowptr, int* __restrict__ cursor){
  __shared__ int s[512];
  int tid = threadIdx.x;
  s[tid] = (tid < NB) ? part[tid] : 0;
  __syncthreads();
  for (int off = 1; off < 512; off <<= 1){
    int t = (tid >= off) ? s[tid-off] : 0;
    __syncthreads();
    s[tid] += t;
    __syncthreads();
  }
  int b = blockIdx.x;
  int base = b ? s[b-1] : 0;
  if (tid < 256){
    int i = b*256 + tid;
    if (i < NN){
      int inclusive = inc[i] + base;
      rowptr[i+1] = inclusive;
      cursor[i] = inclusive - deg[i];
    }
  }
  if (b == 0 && tid == 0) rowptr[0] = 0;
}

__global__ void k_scatter(const int* __restrict__ src, const int* __restrict__ dst,
                          int* __restrict__ cursor, int* __restrict__ srcs){
  int e = blockIdx.x*256 + threadIdx.x;
  if (e < NE){
    int d = dst[e];
    int p = atomicAdd(&cursor[d], 1);
    srcs[p] = src[e];
  }
}

// ---------- per-node pre-transform via MFMA: u(f32) = WpreL*x + b ; vq(bf16-pair) = WpreR*x ----------
__global__ __launch_bounds__(512, 4) void k_uv(
    const float* __restrict__ xin, const uint4* __restrict__ Wpf,
    const float* __restrict__ bpre, float* __restrict__ u, unsigned* __restrict__ vq){
  __shared__ __align__(16) unsigned XH[64*36];
  __shared__ __align__(16) unsigned XL[64*36];
  const int tid = threadIdx.x;
  const int lane = tid & 63;
  const int w = tid >> 6;
  const int t = w >> 1, rg = w & 1;
  const int cc = lane & 31, half = lane >> 5;
  const int col = t*32 + cc;
  uint4 wfr[2][4];
  {
    const uint4* p = Wpf + t*512;
    #pragma unroll
    for (int s = 0; s < 2; s++)
      #pragma unroll
      for (int st = 0; st < 4; st++) wfr[s][st] = p[s*256 + st*64 + lane];
  }
  const float bias = (t < 2) ? bpre[col] : 0.f;
  const int dcol = col & 63;
  const int srow = tid >> 3, sq = tid & 7;

  for (int g = blockIdx.x; g < UVG; g += gridDim.x){
    const int n0 = g*64;
    __syncthreads();                 // previous group's A-frag reads done
    {
      const int node = n0 + srow;
      float4 a = {0,0,0,0}, b = {0,0,0,0};
      if (node < NN){
        a = *(const float4*)&xin[(size_t)node*64 + sq*8];
        b = *(const float4*)&xin[(size_t)node*64 + sq*8 + 4];
      }
      unsigned ax = __float_as_uint(a.x), ay = __float_as_uint(a.y);
      unsigned az = __float_as_uint(a.z), aw = __float_as_uint(a.w);
      unsigned bx = __float_as_uint(b.x), by = __float_as_uint(b.y);
      unsigned bz = __float_as_uint(b.z), bw = __float_as_uint(b.w);
      uint4 hi, lo;
      hi.x = pk_hi(ay, ax); lo.x = pk_lo(a.x, a.y, ax, ay);
      hi.y = pk_hi(aw, az); lo.y = pk_lo(a.z, a.w, az, aw);
      hi.z = pk_hi(by, bx); lo.z = pk_lo(b.x, b.y, bx, by);
      hi.w = pk_hi(bw, bz); lo.w = pk_lo(b.z, b.w, bz, bw);
      *(uint4*)&XH[srow*36 + sq*4] = hi;
      *(uint4*)&XL[srow*36 + sq*4] = lo;
    }
    __syncthreads();
    f32x16 acc = {};
    const int arow = (rg*32 + cc)*36 + half*4;
    #pragma unroll
    for (int st = 0; st < 4; st++){
      uint4 ah = *(const uint4*)&XH[arow + st*8];
      uint4 al = *(const uint4*)&XL[arow + st*8];
      acc = mfma_b(ah, wfr[0][st], acc);
      acc = mfma_b(al, wfr[0][st], acc);
      acc = mfma_b(ah, wfr[1][st], acc);
    }
    if (t < 2){
      #pragma unroll
      for (int r = 0; r < 16; r++){
        int row = n0 + rg*32 + crow(r, half);
        if (row < NN) u[(size_t)row*64 + dcol] = acc[r] + bias;
      }
    } else {
      // pack adjacent columns (even dcol holds pair) -> bf16x2 with RNE
      #pragma unroll
      for (int r = 0; r < 16; r++){
        float val = acc[r];
        float pv = __shfl_xor(val, 1, 64);
        if ((cc & 1) == 0){
          unsigned pk;
          asm("v_cvt_pk_bf16_f32 %0, %1, %2" : "=v"(pk) : "v"(val), "v"(pv));
          int row = n0 + rg*32 + crow(r, half);
          if (row < NN) vq[(size_t)row*32 + (dcol >> 1)] = pk;
        }
      }
    }
  }
}

// ---------- fused CSR gather + MFMA post GEMM (+ fused classifier if EPI==1) ----------
// 512 thr / 8 waves, GN=32; each wave gathers 4 nodes (2 interleaved pairs);
// waves 0,1 do post-MFMA.  v is packed bf16 pairs: 4B/lane/edge.
template<int EPI>
__global__ __launch_bounds__(512, 8) void k_agg(
    const float* __restrict__ xin, const float* __restrict__ u,
    const unsigned* __restrict__ vq,
    const int* __restrict__ rowptr, const int* __restrict__ srcs,
    const uint4* __restrict__ Wcf, const float* __restrict__ bcv,
    const uint4* __restrict__ Wff, const float* __restrict__ bfv,
    float* __restrict__ hout, float* __restrict__ outp){
  __shared__ __align__(16) unsigned Zh[GN*132];
  __shared__ __align__(16) unsigned Zl[GN*132];
  const int tid = threadIdx.x;
  const int lane = tid & 63;
  const int w = tid >> 6;
  const int c = lane & 31;
  const int h = lane >> 5;
  const float bias = (w < 2) ? bcv[w*32 + c] : 0.f;
  const uint4* WH = Wcf + w*1024;
  const uint4* WL = Wcf + (2+w)*1024;

  for (int g = blockIdx.x; g < NGROUPS; g += gridDim.x){
    const int n0 = g*GN;
    __syncthreads();                 // previous group's LDS reads done
    // ---- gather: wave w -> rows w*4 .. w*4+3, processed as 2 interleaved pairs
    #pragma unroll
    for (int pr = 0; pr < 2; pr++){
      const int nA = n0 + w*4 + pr*2;
      const int r0A = rowptr[nA],   r1A = rowptr[nA+1];
      const int r0B = rowptr[nA+1], r1B = rowptr[nA+2];
      // issue first-batch indices for BOTH nodes up front (independent streams)
      int jA = r0A + h, jB = r0B + h;
      int a0=0,a1=0,a2=0,a3=0, b0=0,b1=0,b2=0,b3=0;
      bool hA = (jA + 6 < r1A), hB = (jB + 6 < r1B);
      if (hA){ a0=srcs[jA]; a1=srcs[jA+2]; a2=srcs[jA+4]; a3=srcs[jA+6]; }
      if (hB){ b0=srcs[jB]; b1=srcs[jB+2]; b2=srcs[jB+4]; b3=srcs[jB+6]; }
      #pragma unroll
      for (int sub = 0; sub < 2; sub++){
        const int node = nA + sub;
        const int r1 = sub ? r1B : r1A;
        int jj = sub ? jB : jA;
        int e0 = sub?b0:a0, e1 = sub?b1:a1, e2 = sub?b2:a2, e3 = sub?b3:a3;
        bool have = sub ? hB : hA;
        float Sx = 0.f, Sy = 0.f;
        float Mx = -3.402823466e+38f, My = Mx;
        while (have){
          int njj = jj + 8;
          bool more = (njj + 6 < r1);
          int f0=0,f1=0,f2=0,f3=0;
          if (more){ f0=srcs[njj]; f1=srcs[njj+2]; f2=srcs[njj+4]; f3=srcs[njj+6]; }
          unsigned p0 = vq[(size_t)e0*32 + c];
          unsigned p1 = vq[(size_t)e1*32 + c];
          unsigned p2 = vq[(size_t)e2*32 + c];
          unsigned p3 = vq[(size_t)e3*32 + c];
          float x0 = __uint_as_float(p0 << 16), y0 = __uint_as_float(p0 & 0xFFFF0000u);
          float x1 = __uint_as_float(p1 << 16), y1 = __uint_as_float(p1 & 0xFFFF0000u);
          float x2 = __uint_as_float(p2 << 16), y2 = __uint_as_float(p2 & 0xFFFF0000u);
          float x3 = __uint_as_float(p3 << 16), y3 = __uint_as_float(p3 & 0xFFFF0000u);
          Sx += (x0 + x1) + (x2 + x3);
          Sy += (y0 + y1) + (y2 + y3);
          Mx = fmaxf(Mx, fmaxf(fmaxf(x0, x1), fmaxf(x2, x3)));
          My = fmaxf(My, fmaxf(fmaxf(y0, y1), fmaxf(y2, y3)));
          jj = njj; e0=f0; e1=f1; e2=f2; e3=f3; have = more;
        }
        for (; jj < r1; jj += 2){
          unsigned p = vq[(size_t)srcs[jj]*32 + c];
          float x0 = __uint_as_float(p << 16), y0 = __uint_as_float(p & 0xFFFF0000u);
          Sx += x0; Sy += y0;
          Mx = fmaxf(Mx, x0); My = fmaxf(My, y0);
        }
        Sx += __shfl_xor(Sx, 32, 64);
        Sy += __shfl_xor(Sy, 32, 64);
        Mx = fmaxf(Mx, __shfl_xor(Mx, 32, 64));
        My = fmaxf(My, __shfl_xor(My, 32, 64));

        const float2 up = *(const float2*)&u[(size_t)node*64 + 2*c];
        const float2 xv = *(const float2*)&xin[(size_t)node*64 + 2*c];
        const int d = r1 - (sub ? r0B : r0A);
        float2 z1, z2, z3;
        if (d > 0){
          float fd = (float)d;
          z1.x = up.x + Sx/fd;  z1.y = up.y + Sy/fd;
          z2.x = up.x + Mx;     z2.y = up.y + My;
          z3.x = fmaf(fd, up.x, Sx); z3.y = fmaf(fd, up.y, Sy);
        } else {
          z1.x=z1.y=z2.x=z2.y=z3.x=z3.y=0.f;   // PyG empty-segment semantics
        }
        const int row = w*4 + pr*2 + sub;
        float2 q[4] = {xv, z1, z2, z3};
        #pragma unroll
        for (int qq = 0; qq < 4; qq++){
          unsigned u0 = __float_as_uint(q[qq].x), u1 = __float_as_uint(q[qq].y);
          if (h == 0) Zh[row*132 + qq*32 + c] = pk_hi(u1, u0);
          else        Zl[row*132 + qq*32 + c] = pk_lo(q[qq].x, q[qq].y, u0, u1);
        }
      }
    }
    __syncthreads();
    // ---- post-GEMM MFMA: waves 0,1
    f32x16 acc = {};
    if (w < 2){
      const int arow = c*132 + h*4;
      #pragma unroll 4
      for (int s = 0; s < 16; s++){
        uint4 ah = *(const uint4*)&Zh[arow + s*8];
        uint4 al = *(const uint4*)&Zl[arow + s*8];
        uint4 bh = WH[s*64 + lane];
        uint4 bl = WL[s*64 + lane];
        acc = mfma_b(ah, bh, acc);
        acc = mfma_b(al, bh, acc);
        acc = mfma_b(ah, bl, acc);
      }
      if (EPI == 0){
        #pragma unroll
        for (int r = 0; r < 16; r++){
          float val = fmaxf(acc[r] + bias, 0.f);
          hout[(size_t)(n0 + crow(r,h))*64 + w*32 + c] = val;
        }
      }
    }
    if (EPI == 1){
      __syncthreads();               // BOTH MFMA waves done READING Zh/Zl
      if (w < 2){
        float* HF = (float*)Zh;      // now safe to reuse Zh
        #pragma unroll
        for (int r = 0; r < 16; r++){
          float val = fmaxf(acc[r] + bias, 0.f);
          HF[crow(r,h)*64 + w*32 + c] = val;
        }
      }
      __syncthreads();               // HF complete
      {
        const float* HF = (const float*)Zh;
        unsigned* HH = Zl;
        unsigned* HL = Zl + 1152;
        const int row = tid >> 4, p4 = tid & 15;
        float4 f = *(const float4*)&HF[row*64 + p4*4];
        unsigned f0 = __float_as_uint(f.x), f1 = __float_as_uint(f.y);
        unsigned f2 = __float_as_uint(f.z), f3 = __float_as_uint(f.w);
        HH[row*36 + p4*2]   = pk_hi(f1, f0);
        HH[row*36 + p4*2+1] = pk_hi(f3, f2);
        HL[row*36 + p4*2]   = pk_lo(f.x, f.y, f0, f1);
        HL[row*36 + p4*2+1] = pk_lo(f.z, f.w, f2, f3);
      }
      __syncthreads();               // HH/HL complete
      if (w == 0){
        f32x16 ac2 = {};
        const unsigned* HH = Zl;
        const unsigned* HL = Zl + 1152;
        const int arow = c*36 + h*4;
        #pragma unroll
        for (int st = 0; st < 4; st++){
          uint4 ah = *(const uint4*)&HH[arow + st*8];
          uint4 al = *(const uint4*)&HL[arow + st*8];
          uint4 bh = Wff[st*64 + lane];
          uint4 bl = Wff[256 + st*64 + lane];
          ac2 = mfma_b(ah, bh, ac2);
          ac2 = mfma_b(al, bh, ac2);
          ac2 = mfma_b(ah, bl, ac2);
        }
        const float bcls = bfv[c];
        #pragma unroll
        for (int r = 0; r < 16; r++)
          outp[(size_t)(n0 + crow(r,h))*NCLS + c] = ac2[r] + bcls;
      }
    }
  }
}

extern "C" void kernel_launch(void* const* d_in, const int* in_sizes, int n_in,
                              void* d_out, int out_size, void* d_ws, size_t ws_size,
                              hipStream_t stream){
  const float* x      = (const float*)d_in[0];
  const int*   ei     = (const int*)  d_in[1];
  const int*   src    = ei;
  const int*   dst    = ei + NE;
  const float* W1_pre = (const float*)d_in[2];
  const float* b1_pre = (const float*)d_in[3];
  const float* W1_post= (const float*)d_in[4];
  const float* b1_post= (const float*)d_in[5];
  const float* W1_lin = (const float*)d_in[6];
  const float* b1_lin = (const float*)d_in[7];
  const float* W2_pre = (const float*)d_in[8];
  const float* b2_pre = (const float*)d_in[9];
  const float* W2_post= (const float*)d_in[10];
  const float* b2_post= (const float*)d_in[11];
  const float* W2_lin = (const float*)d_in[12];
  const float* b2_lin = (const float*)d_in[13];
  const float* Wf     = (const float*)d_in[14];
  const float* bf     = (const float*)d_in[15];
  float* out = (float*)d_out;

  size_t off = 0;
  char* ws = (char*)d_ws;
  auto alloc = [&](size_t bytes){ void* p = ws + off; off += (bytes + 255) & ~(size_t)255; return p; };
  int*      deg    = (int*)     alloc(NN*4);
  int*      rowptr = (int*)     alloc((NN+1)*4);
  int*      cursor = (int*)     alloc(NN*4);
  int*      inc    = (int*)     alloc(NB*256*4);
  int*      part   = (int*)     alloc(512*4);
  int*      srcs   = (int*)     alloc((size_t)NE*4);
  float*    u      = (float*)   alloc((size_t)NN*64*4);
  unsigned* vq     = (unsigned*)alloc((size_t)NN*32*4);
  float*    h1     = (float*)   alloc((size_t)NN*64*4);
  uint4*    Wcf    = (uint4*)   alloc(2*4096*16);
  uint4*    Wpf    = (uint4*)   alloc(4096*16);
  uint4*    Wff    = (uint4*)   alloc(512*16);
  float*    bc     = (float*)   alloc(128*4);

  // 1. all weight fragments + bc + zero deg, in one kernel
  k_setup<<<417, 256, 0, stream>>>(W1_lin, b1_lin, W1_post, b1_post,
                                   W2_lin, b2_lin, W2_post, b2_post,
                                   W1_pre, W2_pre, Wf, Wcf, Wpf, Wff, bc, deg);
  // 2-5. CSR build
  k_deg    <<<(NE+255)/256, 256, 0, stream>>>(dst, deg);
  k_scan1  <<<NB, 256, 0, stream>>>(deg, inc, part);
  k_scan23 <<<NB, 512, 0, stream>>>(inc, part, deg, rowptr, cursor);
  k_scatter<<<(NE+255)/256, 256, 0, stream>>>(src, dst, cursor, srcs);

  // layer 1
  k_uv    <<<1024, 512, 0, stream>>>(x, Wpf, b1_pre, u, vq);
  k_agg<0><<<2048, 512, 0, stream>>>(x, u, vq, rowptr, srcs, Wcf, bc,
                                     nullptr, nullptr, h1, nullptr);

  // layer 2 (+ fused classifier; h2 never hits HBM)
  k_uv    <<<1024, 512, 0, stream>>>(h1, Wpf + 2048, b2_pre, u, vq);
  k_agg<1><<<2048, 512, 0, stream>>>(h1, u, vq, rowptr, srcs, Wcf + 4096, bc + 64,
                                     Wff, bf, nullptr, out);
}

// Round 10
// 298.360 us; speedup vs baseline: 11.7864x; 1.0391x over previous
//
#include <hip/hip_runtime.h>

#define NN 100000
#define NE 1000000
#define NCLS 32
#define NB 391            // ceil(NN/256)
#define GN 32             // nodes per k_agg group
#define NGROUPS (NN/GN)   // 3125
#define UVG ((NN+63)/64)  // 1563 uv groups of 64 nodes

typedef __bf16 bf16x8 __attribute__((ext_vector_type(8)));
typedef float f32x16 __attribute__((ext_vector_type(16)));

__device__ __forceinline__ int imin(int a, int b){ return a < b ? a : b; }

// pack hi16 of two f32 into one u32: {hi16(f1) : hi16(f0)}  (f0 -> low half)
__device__ __forceinline__ unsigned pk_hi(unsigned u1, unsigned u0){
  return __builtin_amdgcn_perm(u1, u0, 0x07060302u);
}
__device__ __forceinline__ unsigned pk_lo(float f0, float f1, unsigned u0, unsigned u1){
  float r0 = f0 - __uint_as_float(u0 & 0xFFFF0000u);
  float r1 = f1 - __uint_as_float(u1 & 0xFFFF0000u);
  return pk_hi(__float_as_uint(r1), __float_as_uint(r0));
}
__device__ __forceinline__ f32x16 mfma_b(uint4 a, uint4 b, f32x16 c){
  bf16x8 av, bv;
  __builtin_memcpy(&av, &a, 16);
  __builtin_memcpy(&bv, &b, 16);
  return __builtin_amdgcn_mfma_f32_32x32x16_bf16(av, bv, c, 0, 0, 0);
}
__device__ __forceinline__ int crow(int r, int half){ return (r&3) + 8*(r>>2) + 4*half; }

// ---------- one-shot setup: all weight fragments + bc + zero deg ----------
__global__ void k_setup(const float* __restrict__ W1_lin, const float* __restrict__ b1_lin,
                        const float* __restrict__ W1_post, const float* __restrict__ b1_post,
                        const float* __restrict__ W2_lin, const float* __restrict__ b2_lin,
                        const float* __restrict__ W2_post, const float* __restrict__ b2_post,
                        const float* __restrict__ W1_pre, const float* __restrict__ W2_pre,
                        const float* __restrict__ Wf,
                        uint4* __restrict__ Wcf, uint4* __restrict__ Wpf,
                        uint4* __restrict__ Wff, float* __restrict__ bc,
                        int* __restrict__ deg){
  const int blk = blockIdx.x, tid = threadIdx.x;
  if (blk < 16){
    int i = blk*256 + tid;                    // [0, 4096)
    int layer = i >> 11;
    int t = (i >> 10) & 1, step = (i >> 6) & 15, lane = i & 63;
    const float* Wlin  = layer ? W2_lin  : W1_lin;
    const float* Wpost = layer ? W2_post : W1_post;
    int col = t*32 + (lane & 31);
    int k0 = step*16 + ((lane >> 5) << 3);
    unsigned hi[4], lo[4];
    for (int p = 0; p < 4; p++){
      float f0 = 0.f, f1 = 0.f;
      for (int j = 0; j < 64; j++){
        float wl = Wlin[col*64 + j];
        f0 += wl * Wpost[j*256 + k0 + 2*p];
        f1 += wl * Wpost[j*256 + k0 + 2*p + 1];
      }
      unsigned u0 = __float_as_uint(f0), u1 = __float_as_uint(f1);
      hi[p] = pk_hi(u1, u0);
      lo[p] = pk_lo(f0, f1, u0, u1);
    }
    uint4* base = Wcf + layer*4096;
    base[t*1024     + step*64 + lane] = make_uint4(hi[0],hi[1],hi[2],hi[3]);
    base[(2+t)*1024 + step*64 + lane] = make_uint4(lo[0],lo[1],lo[2],lo[3]);
  } else if (blk < 24){
    int i = (blk-16)*256 + tid;               // [0, 2048)
    int layer = i >> 10;
    int t = (i >> 8) & 3, st = (i >> 6) & 3, lane = i & 63;
    const float* Wpre = layer ? W2_pre : W1_pre;
    int col = t*32 + (lane & 31);             // 0..127 (u | v)
    int o = col & 63, koff = (col >> 6) * 64;
    int k0 = st*16 + ((lane >> 5) << 3);
    unsigned hi[4], lo[4];
    for (int p = 0; p < 4; p++){
      float f0 = Wpre[o*128 + koff + k0 + 2*p];
      float f1 = Wpre[o*128 + koff + k0 + 2*p + 1];
      unsigned u0 = __float_as_uint(f0), u1 = __float_as_uint(f1);
      hi[p] = pk_hi(u1, u0);
      lo[p] = pk_lo(f0, f1, u0, u1);
    }
    uint4* base = Wpf + layer*2048 + t*512;
    base[st*64 + lane]       = make_uint4(hi[0],hi[1],hi[2],hi[3]);
    base[256 + st*64 + lane] = make_uint4(lo[0],lo[1],lo[2],lo[3]);
  } else if (blk == 24){
    int st = tid >> 6, lane = tid & 63;       // 256 threads exactly
    int cls = lane & 31;
    int k0 = st*16 + ((lane >> 5) << 3);
    unsigned hi[4], lo[4];
    for (int p = 0; p < 4; p++){
      float f0 = Wf[cls*64 + k0 + 2*p];
      float f1 = Wf[cls*64 + k0 + 2*p + 1];
      unsigned u0 = __float_as_uint(f0), u1 = __float_as_uint(f1);
      hi[p] = pk_hi(u1, u0);
      lo[p] = pk_lo(f0, f1, u0, u1);
    }
    Wff[st*64 + lane]       = make_uint4(hi[0],hi[1],hi[2],hi[3]);
    Wff[256 + st*64 + lane] = make_uint4(lo[0],lo[1],lo[2],lo[3]);
  } else if (blk == 25){
    if (tid < 128){
      int layer = tid >> 6, o = tid & 63;
      const float* Wlin  = layer ? W2_lin  : W1_lin;
      const float* blin  = layer ? b2_lin  : b1_lin;
      const float* bpost = layer ? b2_post : b1_post;
      float s = blin[o];
      for (int j = 0; j < 64; j++) s += Wlin[o*64+j] * bpost[j];
      bc[tid] = s;
    }
  } else {
    int i = (blk-26)*256 + tid;
    if (i < NN) deg[i] = 0;
  }
}

// ---------- CSR build ----------
__global__ void k_deg(const int* __restrict__ dst, int* __restrict__ deg){
  int e = blockIdx.x*256 + threadIdx.x;
  if (e < NE) atomicAdd(&deg[dst[e]], 1);
}

__global__ void k_scan1(const int* __restrict__ deg, int* __restrict__ inc,
                        int* __restrict__ part){
  __shared__ int s[256];
  int tid = threadIdx.x;
  int i = blockIdx.x*256 + tid;
  s[tid] = (i < NN) ? deg[i] : 0;
  __syncthreads();
  for (int off = 1; off < 256; off <<= 1){
    int t = (tid >= off) ? s[tid-off] : 0;
    __syncthreads();
    s[tid] += t;
    __syncthreads();
  }
  inc[i] = s[tid];
  if (tid == 255) part[blockIdx.x] = s[255];
}

// each block re-scans all partials in LDS, then emits rowptr + cursor
__global__ void k_scan23(const int* __restrict__ inc, const int* __restrict__ part,
                         const int* __restrict__ deg,
                         int* __restrict__ rowptr, int* __restrict__ cursor){
  __shared__ int s[512];
  int tid = threadIdx.x;
  s[tid] = (tid < NB) ? part[tid] : 0;
  __syncthreads();
  for (int off = 1; off < 512; off <<= 1){
    int t = (tid >= off) ? s[tid-off] : 0;
    __syncthreads();
    s[tid] += t;
    __syncthreads();
  }
  int b = blockIdx.x;
  int base = b ? s[b-1] : 0;
  if (tid < 256){
    int i = b*256 + tid;
    if (i < NN){
      int inclusive = inc[i] + base;
      rowptr[i+1] = inclusive;
      cursor[i] = inclusive - deg[i];
    }
  }
  if (b == 0 && tid == 0) rowptr[0] = 0;
}

__global__ void k_scatter(const int* __restrict__ src, const int* __restrict__ dst,
                          int* __restrict__ cursor, int* __restrict__ srcs){
  int e = blockIdx.x*256 + threadIdx.x;
  if (e < NE){
    int d = dst[e];
    int p = atomicAdd(&cursor[d], 1);
    srcs[p] = src[e];
  }
}

// ---------- per-node pre-transform via MFMA: u(f32) = WpreL*x + b ; vq(bf16-pair) = WpreR*x ----------
__global__ __launch_bounds__(512, 4) void k_uv(
    const float* __restrict__ xin, const uint4* __restrict__ Wpf,
    const float* __restrict__ bpre, float* __restrict__ u, unsigned* __restrict__ vq){
  __shared__ __align__(16) unsigned XH[64*36];
  __shared__ __align__(16) unsigned XL[64*36];
  const int tid = threadIdx.x;
  const int lane = tid & 63;
  const int w = tid >> 6;
  const int t = w >> 1, rg = w & 1;
  const int cc = lane & 31, half = lane >> 5;
  const int col = t*32 + cc;
  uint4 wfr[2][4];
  {
    const uint4* p = Wpf + t*512;
    #pragma unroll
    for (int s = 0; s < 2; s++)
      #pragma unroll
      for (int st = 0; st < 4; st++) wfr[s][st] = p[s*256 + st*64 + lane];
  }
  const float bias = (t < 2) ? bpre[col] : 0.f;
  const int dcol = col & 63;
  const int srow = tid >> 3, sq = tid & 7;

  for (int g = blockIdx.x; g < UVG; g += gridDim.x){
    const int n0 = g*64;
    __syncthreads();                 // previous group's A-frag reads done
    {
      const int node = n0 + srow;
      float4 a = {0,0,0,0}, b = {0,0,0,0};
      if (node < NN){
        a = *(const float4*)&xin[(size_t)node*64 + sq*8];
        b = *(const float4*)&xin[(size_t)node*64 + sq*8 + 4];
      }
      unsigned ax = __float_as_uint(a.x), ay = __float_as_uint(a.y);
      unsigned az = __float_as_uint(a.z), aw = __float_as_uint(a.w);
      unsigned bx = __float_as_uint(b.x), by = __float_as_uint(b.y);
      unsigned bz = __float_as_uint(b.z), bw = __float_as_uint(b.w);
      uint4 hi, lo;
      hi.x = pk_hi(ay, ax); lo.x = pk_lo(a.x, a.y, ax, ay);
      hi.y = pk_hi(aw, az); lo.y = pk_lo(a.z, a.w, az, aw);
      hi.z = pk_hi(by, bx); lo.z = pk_lo(b.x, b.y, bx, by);
      hi.w = pk_hi(bw, bz); lo.w = pk_lo(b.z, b.w, bz, bw);
      *(uint4*)&XH[srow*36 + sq*4] = hi;
      *(uint4*)&XL[srow*36 + sq*4] = lo;
    }
    __syncthreads();
    f32x16 acc = {};
    const int arow = (rg*32 + cc)*36 + half*4;
    #pragma unroll
    for (int st = 0; st < 4; st++){
      uint4 ah = *(const uint4*)&XH[arow + st*8];
      uint4 al = *(const uint4*)&XL[arow + st*8];
      acc = mfma_b(ah, wfr[0][st], acc);
      acc = mfma_b(al, wfr[0][st], acc);
      acc = mfma_b(ah, wfr[1][st], acc);
    }
    if (t < 2){
      #pragma unroll
      for (int r = 0; r < 16; r++){
        int row = n0 + rg*32 + crow(r, half);
        if (row < NN) u[(size_t)row*64 + dcol] = acc[r] + bias;
      }
    } else {
      // pack adjacent columns (even dcol holds pair) -> bf16x2 with RNE
      #pragma unroll
      for (int r = 0; r < 16; r++){
        float val = acc[r];
        float pv = __shfl_xor(val, 1, 64);
        if ((cc & 1) == 0){
          unsigned pk;
          asm("v_cvt_pk_bf16_f32 %0, %1, %2" : "=v"(pk) : "v"(val), "v"(pv));
          int row = n0 + rg*32 + crow(r, half);
          if (row < NN) vq[(size_t)row*32 + (dcol >> 1)] = pk;
        }
      }
    }
  }
}

// ---------- fused CSR gather + MFMA post GEMM (+ fused classifier if EPI==1) ----------
// 512 thr / 8 waves, GN=32; each wave gathers 4 nodes via fully-predicated,
// dual-node-interleaved, index-prefetched batches (no serial remainder).
// Masked slots clamp index to r1-1 (same node) -> idempotent for max; sum masked.
template<int EPI>
__global__ __launch_bounds__(512, 8) void k_agg(
    const float* __restrict__ xin, const float* __restrict__ u,
    const unsigned* __restrict__ vq,
    const int* __restrict__ rowptr, const int* __restrict__ srcs,
    const uint4* __restrict__ Wcf, const float* __restrict__ bcv,
    const uint4* __restrict__ Wff, const float* __restrict__ bfv,
    float* __restrict__ hout, float* __restrict__ outp){
  __shared__ __align__(16) unsigned Zh[GN*132];
  __shared__ __align__(16) unsigned Zl[GN*132];
  const int tid = threadIdx.x;
  const int lane = tid & 63;
  const int w = tid >> 6;
  const int c = lane & 31;
  const int h = lane >> 5;
  const float bias = (w < 2) ? bcv[w*32 + c] : 0.f;
  const uint4* WH = Wcf + w*1024;
  const uint4* WL = Wcf + (2+w)*1024;
  const float NINF = -3.402823466e+38f;

  for (int g = blockIdx.x; g < NGROUPS; g += gridDim.x){
    const int n0 = g*GN;
    __syncthreads();                 // previous group's LDS reads done
    // ---- gather: wave w -> rows w*4 .. w*4+3, as 2 interleaved node pairs
    #pragma unroll
    for (int pr = 0; pr < 2; pr++){
      const int nA = n0 + w*4 + pr*2;
      const int r0A = rowptr[nA],   r1A = rowptr[nA+1];
      const int r0B = rowptr[nA+1], r1B = rowptr[nA+2];
      const int dA = r1A - r0A, dB = r1B - r0B;
      const int nbA = (((dA + 1) >> 1) + 3) >> 2;   // batches (h=0 slot count)
      const int nbB = (((dB + 1) >> 1) + 3) >> 2;
      const int nb  = nbA > nbB ? nbA : nbB;
      const int jA0 = r0A + h, jB0 = r0B + h;
      int iA0=0,iA1=0,iA2=0,iA3=0, iB0=0,iB1=0,iB2=0,iB3=0;
      if (nbA){
        int e1 = r1A - 1;
        iA0 = srcs[imin(jA0,   e1)]; iA1 = srcs[imin(jA0+2, e1)];
        iA2 = srcs[imin(jA0+4, e1)]; iA3 = srcs[imin(jA0+6, e1)];
      }
      if (nbB){
        int e1 = r1B - 1;
        iB0 = srcs[imin(jB0,   e1)]; iB1 = srcs[imin(jB0+2, e1)];
        iB2 = srcs[imin(jB0+4, e1)]; iB3 = srcs[imin(jB0+6, e1)];
      }
      float SxA=0.f, SyA=0.f, MxA=NINF, MyA=NINF;
      float SxB=0.f, SyB=0.f, MxB=NINF, MyB=NINF;
      for (int t = 0; t < nb; t++){
        if (t < nbA){
          unsigned p0 = vq[(size_t)iA0*32 + c];
          unsigned p1 = vq[(size_t)iA1*32 + c];
          unsigned p2 = vq[(size_t)iA2*32 + c];
          unsigned p3 = vq[(size_t)iA3*32 + c];
          if (t+1 < nbA){
            int jn = jA0 + 8*(t+1), e1 = r1A - 1;
            iA0 = srcs[imin(jn,   e1)]; iA1 = srcs[imin(jn+2, e1)];
            iA2 = srcs[imin(jn+4, e1)]; iA3 = srcs[imin(jn+6, e1)];
          }
          const int j = jA0 + 8*t;
          float x0 = __uint_as_float(p0 << 16), y0 = __uint_as_float(p0 & 0xFFFF0000u);
          float x1 = __uint_as_float(p1 << 16), y1 = __uint_as_float(p1 & 0xFFFF0000u);
          float x2 = __uint_as_float(p2 << 16), y2 = __uint_as_float(p2 & 0xFFFF0000u);
          float x3 = __uint_as_float(p3 << 16), y3 = __uint_as_float(p3 & 0xFFFF0000u);
          // max: clamped duplicates are same-node edges -> idempotent, no mask
          MxA = fmaxf(MxA, fmaxf(fmaxf(x0, x1), fmaxf(x2, x3)));
          MyA = fmaxf(MyA, fmaxf(fmaxf(y0, y1), fmaxf(y2, y3)));
          // sum: mask OOB slots
          SxA += ((j   < r1A) ? x0 : 0.f) + ((j+2 < r1A) ? x1 : 0.f)
               + ((j+4 < r1A) ? x2 : 0.f) + ((j+6 < r1A) ? x3 : 0.f);
          SyA += ((j   < r1A) ? y0 : 0.f) + ((j+2 < r1A) ? y1 : 0.f)
               + ((j+4 < r1A) ? y2 : 0.f) + ((j+6 < r1A) ? y3 : 0.f);
        }
        if (t < nbB){
          unsigned p0 = vq[(size_t)iB0*32 + c];
          unsigned p1 = vq[(size_t)iB1*32 + c];
          unsigned p2 = vq[(size_t)iB2*32 + c];
          unsigned p3 = vq[(size_t)iB3*32 + c];
          if (t+1 < nbB){
            int jn = jB0 + 8*(t+1), e1 = r1B - 1;
            iB0 = srcs[imin(jn,   e1)]; iB1 = srcs[imin(jn+2, e1)];
            iB2 = srcs[imin(jn+4, e1)]; iB3 = srcs[imin(jn+6, e1)];
          }
          const int j = jB0 + 8*t;
          float x0 = __uint_as_float(p0 << 16), y0 = __uint_as_float(p0 & 0xFFFF0000u);
          float x1 = __uint_as_float(p1 << 16), y1 = __uint_as_float(p1 & 0xFFFF0000u);
          float x2 = __uint_as_float(p2 << 16), y2 = __uint_as_float(p2 & 0xFFFF0000u);
          float x3 = __uint_as_float(p3 << 16), y3 = __uint_as_float(p3 & 0xFFFF0000u);
          MxB = fmaxf(MxB, fmaxf(fmaxf(x0, x1), fmaxf(x2, x3)));
          MyB = fmaxf(MyB, fmaxf(fmaxf(y0, y1), fmaxf(y2, y3)));
          SxB += ((j   < r1B) ? x0 : 0.f) + ((j+2 < r1B) ? x1 : 0.f)
               + ((j+4 < r1B) ? x2 : 0.f) + ((j+6 < r1B) ? x3 : 0.f);
          SyB += ((j   < r1B) ? y0 : 0.f) + ((j+2 < r1B) ? y1 : 0.f)
               + ((j+4 < r1B) ? y2 : 0.f) + ((j+6 < r1B) ? y3 : 0.f);
        }
      }
      // finalize both nodes
      #pragma unroll
      for (int sub = 0; sub < 2; sub++){
        const int node = nA + sub;
        const int d = sub ? dB : dA;
        float Sx = sub ? SxB : SxA, Sy = sub ? SyB : SyA;
        float Mx = sub ? MxB : MxA, My = sub ? MyB : MyA;
        Sx += __shfl_xor(Sx, 32, 64);
        Sy += __shfl_xor(Sy, 32, 64);
        Mx = fmaxf(Mx, __shfl_xor(Mx, 32, 64));
        My = fmaxf(My, __shfl_xor(My, 32, 64));
        const float2 up = *(const float2*)&u[(size_t)node*64 + 2*c];
        const float2 xv = *(const float2*)&xin[(size_t)node*64 + 2*c];
        float2 z1, z2, z3;
        if (d > 0){
          float fd = (float)d;
          z1.x = up.x + Sx/fd;  z1.y = up.y + Sy/fd;
          z2.x = up.x + Mx;     z2.y = up.y + My;
          z3.x = fmaf(fd, up.x, Sx); z3.y = fmaf(fd, up.y, Sy);
        } else {
          z1.x=z1.y=z2.x=z2.y=z3.x=z3.y=0.f;   // PyG empty-segment semantics
        }
        const int row = w*4 + pr*2 + sub;
        float2 q[4] = {xv, z1, z2, z3};
        #pragma unroll
        for (int qq = 0; qq < 4; qq++){
          unsigned u0 = __float_as_uint(q[qq].x), u1 = __float_as_uint(q[qq].y);
          if (h == 0) Zh[row*132 + qq*32 + c] = pk_hi(u1, u0);
          else        Zl[row*132 + qq*32 + c] = pk_lo(q[qq].x, q[qq].y, u0, u1);
        }
      }
    }
    __syncthreads();
    // ---- post-GEMM MFMA: waves 0,1
    f32x16 acc = {};
    if (w < 2){
      const int arow = c*132 + h*4;
      #pragma unroll 4
      for (int s = 0; s < 16; s++){
        uint4 ah = *(const uint4*)&Zh[arow + s*8];
        uint4 al = *(const uint4*)&Zl[arow + s*8];
        uint4 bh = WH[s*64 + lane];
        uint4 bl = WL[s*64 + lane];
        acc = mfma_b(ah, bh, acc);
        acc = mfma_b(al, bh, acc);
        acc = mfma_b(ah, bl, acc);
      }
      if (EPI == 0){
        #pragma unroll
        for (int r = 0; r < 16; r++){
          float val = fmaxf(acc[r] + bias, 0.f);
          hout[(size_t)(n0 + crow(r,h))*64 + w*32 + c] = val;
        }
      }
    }
    if (EPI == 1){
      __syncthreads();               // BOTH MFMA waves done READING Zh/Zl
      if (w < 2){
        float* HF = (float*)Zh;      // now safe to reuse Zh
        #pragma unroll
        for (int r = 0; r < 16; r++){
          float val = fmaxf(acc[r] + bias, 0.f);
          HF[crow(r,h)*64 + w*32 + c] = val;
        }
      }
      __syncthreads();               // HF complete
      {
        const float* HF = (const float*)Zh;
        unsigned* HH = Zl;
        unsigned* HL = Zl + 1152;
        const int row = tid >> 4, p4 = tid & 15;
        float4 f = *(const float4*)&HF[row*64 + p4*4];
        unsigned f0 = __float_as_uint(f.x), f1 = __float_as_uint(f.y);
        unsigned f2 = __float_as_uint(f.z), f3 = __float_as_uint(f.w);
        HH[row*36 + p4*2]   = pk_hi(f1, f0);
        HH[row*36 + p4*2+1] = pk_hi(f3, f2);
        HL[row*36 + p4*2]   = pk_lo(f.x, f.y, f0, f1);
        HL[row*36 + p4*2+1] = pk_lo(f.z, f.w, f2, f3);
      }
      __syncthreads();               // HH/HL complete
      if (w == 0){
        f32x16 ac2 = {};
        const unsigned* HH = Zl;
        const unsigned* HL = Zl + 1152;
        const int arow = c*36 + h*4;
        #pragma unroll
        for (int st = 0; st < 4; st++){
          uint4 ah = *(const uint4*)&HH[arow + st*8];
          uint4 al = *(const uint4*)&HL[arow + st*8];
          uint4 bh = Wff[st*64 + lane];
          uint4 bl = Wff[256 + st*64 + lane];
          ac2 = mfma_b(ah, bh, ac2);
          ac2 = mfma_b(al, bh, ac2);
          ac2 = mfma_b(ah, bl, ac2);
        }
        const float bcls = bfv[c];
        #pragma unroll
        for (int r = 0; r < 16; r++)
          outp[(size_t)(n0 + crow(r,h))*NCLS + c] = ac2[r] + bcls;
      }
    }
  }
}

extern "C" void kernel_launch(void* const* d_in, const int* in_sizes, int n_in,
                              void* d_out, int out_size, void* d_ws, size_t ws_size,
                              hipStream_t stream){
  const float* x      = (const float*)d_in[0];
  const int*   ei     = (const int*)  d_in[1];
  const int*   src    = ei;
  const int*   dst    = ei + NE;
  const float* W1_pre = (const float*)d_in[2];
  const float* b1_pre = (const float*)d_in[3];
  const float* W1_post= (const float*)d_in[4];
  const float* b1_post= (const float*)d_in[5];
  const float* W1_lin = (const float*)d_in[6];
  const float* b1_lin = (const float*)d_in[7];
  const float* W2_pre = (const float*)d_in[8];
  const float* b2_pre = (const float*)d_in[9];
  const float* W2_post= (const float*)d_in[10];
  const float* b2_post= (const float*)d_in[11];
  const float* W2_lin = (const float*)d_in[12];
  const float* b2_lin = (const float*)d_in[13];
  const float* Wf     = (const float*)d_in[14];
  const float* bf     = (const float*)d_in[15];
  float* out = (float*)d_out;

  size_t off = 0;
  char* ws = (char*)d_ws;
  auto alloc = [&](size_t bytes){ void* p = ws + off; off += (bytes + 255) & ~(size_t)255; return p; };
  int*      deg    = (int*)     alloc(NN*4);
  int*      rowptr = (int*)     alloc((NN+1)*4);
  int*      cursor = (int*)     alloc(NN*4);
  int*      inc    = (int*)     alloc(NB*256*4);
  int*      part   = (int*)     alloc(512*4);
  int*      srcs   = (int*)     alloc((size_t)NE*4);
  float*    u      = (float*)   alloc((size_t)NN*64*4);
  unsigned* vq     = (unsigned*)alloc((size_t)NN*32*4);
  float*    h1     = (float*)   alloc((size_t)NN*64*4);
  uint4*    Wcf    = (uint4*)   alloc(2*4096*16);
  uint4*    Wpf    = (uint4*)   alloc(4096*16);
  uint4*    Wff    = (uint4*)   alloc(512*16);
  float*    bc     = (float*)   alloc(128*4);

  // 1. all weight fragments + bc + zero deg, in one kernel
  k_setup<<<417, 256, 0, stream>>>(W1_lin, b1_lin, W1_post, b1_post,
                                   W2_lin, b2_lin, W2_post, b2_post,
                                   W1_pre, W2_pre, Wf, Wcf, Wpf, Wff, bc, deg);
  // 2-5. CSR build
  k_deg    <<<(NE+255)/256, 256, 0, stream>>>(dst, deg);
  k_scan1  <<<NB, 256, 0, stream>>>(deg, inc, part);
  k_scan23 <<<NB, 512, 0, stream>>>(inc, part, deg, rowptr, cursor);
  k_scatter<<<(NE+255)/256, 256, 0, stream>>>(src, dst, cursor, srcs);

  // layer 1
  k_uv    <<<UVG, 512, 0, stream>>>(x, Wpf, b1_pre, u, vq);
  k_agg<0><<<NGROUPS, 512, 0, stream>>>(x, u, vq, rowptr, srcs, Wcf, bc,
                                        nullptr, nullptr, h1, nullptr);

  // layer 2 (+ fused classifier; h2 never hits HBM)
  k_uv    <<<UVG, 512, 0, stream>>>(h1, Wpf + 2048, b2_pre, u, vq);
  k_agg<1><<<NGROUPS, 512, 0, stream>>>(h1, u, vq, rowptr, srcs, Wcf + 4096, bc + 64,
                                        Wff, bf, nullptr, out);
}